// Round 10
// baseline (5103.592 us; speedup 1.0000x reference)
//
#include <hip/hip_runtime.h>
#include <hip/hip_bf16.h>
#include <cstddef>
#include <cstdint>

#define Sdim 64
#define Tdim 64
#define Bdim 128
#define Hdim 1024
#define H3 3072
#define TB (Tdim * Bdim)
#define SB (Sdim * Bdim)
#define NWG 256

typedef __attribute__((ext_vector_type(4))) float f32x4;
typedef __attribute__((ext_vector_type(8))) short bf16x8;

__device__ __forceinline__ float rcpf(float x) { return __builtin_amdgcn_rcpf(x); }
__device__ __forceinline__ float sigf(float x) { return rcpf(1.0f + __expf(-x)); }
__device__ __forceinline__ float tanh_fast(float x) {
  x = fminf(fmaxf(x, -15.0f), 15.0f);
  float t = __expf(2.0f * x);
  return (t - 1.0f) * rcpf(t + 1.0f);
}
__device__ __forceinline__ float bl(uint32_t u) { return __uint_as_float(u << 16); }
__device__ __forceinline__ float bh(uint32_t u) { return __uint_as_float(u & 0xffff0000u); }
__device__ __forceinline__ float b2f(uint16_t v) { return __uint_as_float((uint32_t)v << 16); }
__device__ __forceinline__ uint16_t f2b(float f) {
  __hip_bfloat16 h = __float2bfloat16(f);
  return *reinterpret_cast<uint16_t*>(&h);
}

// ---- relaxed agent-scope (cache-bypassing, coherent) accessors ----
__device__ __forceinline__ uint32_t ald32(const void* p) {
  return __hip_atomic_load((const uint32_t*)p, __ATOMIC_RELAXED, __HIP_MEMORY_SCOPE_AGENT);
}
__device__ __forceinline__ unsigned long long ald64(const void* p) {
  return __hip_atomic_load((const unsigned long long*)p, __ATOMIC_RELAXED, __HIP_MEMORY_SCOPE_AGENT);
}
__device__ __forceinline__ void ast32(void* p, uint32_t v) {
  __hip_atomic_store((uint32_t*)p, v, __ATOMIC_RELAXED, __HIP_MEMORY_SCOPE_AGENT);
}
__device__ __forceinline__ void ast64(void* p, unsigned long long v) {
  __hip_atomic_store((unsigned long long*)p, v, __ATOMIC_RELAXED, __HIP_MEMORY_SCOPE_AGENT);
}
__device__ __forceinline__ float aldf(const void* p) { return __uint_as_float(ald32(p)); }
__device__ __forceinline__ void astf(void* p, float v) { ast32(p, __float_as_uint(v)); }
__device__ __forceinline__ uint4 ald128(const void* p) {
  unsigned long long a = ald64(p);
  unsigned long long b = ald64((const char*)p + 8);
  uint4 r;
  r.x = (uint32_t)a; r.y = (uint32_t)(a >> 32);
  r.z = (uint32_t)b; r.w = (uint32_t)(b >> 32);
  return r;
}
#define PK2(x, y) ((unsigned long long)__float_as_uint(x) | ((unsigned long long)__float_as_uint(y) << 32))
__device__ __forceinline__ float ulo(unsigned long long u) { return __uint_as_float((uint32_t)u); }
__device__ __forceinline__ float uhi(unsigned long long u) { return __uint_as_float((uint32_t)(u >> 32)); }

// ---------------------------------------------------------------- mgemm ----
struct MDesc {
  const uint16_t* A0; const uint16_t* B0;
  const uint16_t* A1; const uint16_t* B1;
  const uint16_t* A2; const uint16_t* B2;
  const float* bias0; const float* bias1; const float* bias2;
  float* C;
  int M, N, K;
};

template<int BM, int BN, int MODE>
__global__ __launch_bounds__(256) void mgemm(MDesc d, const float* __restrict__ ymask,
                                             float* __restrict__ outp)
{
  const int nb = blockIdx.x * BN;
  const int mb = blockIdx.y * BM;
  if (nb >= d.N || mb >= d.M) return;

  __shared__ char lds[(BM + BN) * 128];
  char* As = lds;
  char* Bs = lds + BM * 128;

  const int t = threadIdx.x;
  const int lane = t & 63;
  const int wid = t >> 6;
  const int wm = wid >> 1, wn = wid & 1;
  constexpr int WM = BM / 2, WN = BN / 2;
  constexpr int MR = WM / 16, NR = WN / 16;
  constexpr int CA = BM / 32;
  constexpr int CB = BN / 32;

  const int arow_base = wm * WM + (lane & 15);
  const int brow_base = wn * WN + (lane & 15);
  const int akb = (lane >> 4) * 16;
  const int axA = (arow_base & 7) << 4;
  const int axB = (brow_base & 7) << 4;

  f32x4 acc[MR][NR];
  #pragma unroll
  for (int m = 0; m < MR; ++m)
    #pragma unroll
    for (int n = 0; n < NR; ++n)
      acc[m][n] = (f32x4){0.f, 0.f, 0.f, 0.f};

  const int K = d.K;
  const int nkt = K / 64;

  #pragma unroll 1
  for (int p = 0; p < 3; ++p) {
    const uint16_t* A = (p == 0) ? d.A0 : (p == 1 ? d.A1 : d.A2);
    const uint16_t* B = (p == 0) ? d.B0 : (p == 1 ? d.B1 : d.B2);
    if (A == nullptr) break;

    const char* gA[CA]; int lA[CA];
    const char* gB[CB]; int lB[CB];
    #pragma unroll
    for (int c = 0; c < CA; ++c) {
      int i = c * 256 + t, row = i >> 3, kb = (i & 7) * 16;
      gA[c] = (const char*)A + (size_t)(mb + row) * K * 2 + kb;
      lA[c] = row * 128 + (kb ^ ((row & 7) << 4));
    }
    #pragma unroll
    for (int c = 0; c < CB; ++c) {
      int i = c * 256 + t, row = i >> 3, kb = (i & 7) * 16;
      gB[c] = (const char*)B + (size_t)(nb + row) * K * 2 + kb;
      lB[c] = row * 128 + (kb ^ ((row & 7) << 4));
    }

    uint4 ra[CA], rb[CB];
    #pragma unroll
    for (int c = 0; c < CA; ++c) ra[c] = *(const uint4*)gA[c];
    #pragma unroll
    for (int c = 0; c < CB; ++c) rb[c] = *(const uint4*)gB[c];

    for (int kk = 0; kk < nkt; ++kk) {
      __syncthreads();
      #pragma unroll
      for (int c = 0; c < CA; ++c) *(uint4*)(As + lA[c]) = ra[c];
      #pragma unroll
      for (int c = 0; c < CB; ++c) *(uint4*)(Bs + lB[c]) = rb[c];
      __syncthreads();
      if (kk + 1 < nkt) {
        #pragma unroll
        for (int c = 0; c < CA; ++c) ra[c] = *(const uint4*)(gA[c] + (size_t)(kk + 1) * 128);
        #pragma unroll
        for (int c = 0; c < CB; ++c) rb[c] = *(const uint4*)(gB[c] + (size_t)(kk + 1) * 128);
      }
      #pragma unroll
      for (int ks = 0; ks < 2; ++ks) {
        bf16x8 av[MR], bv[NR];
        #pragma unroll
        for (int m = 0; m < MR; ++m) {
          int row = arow_base + m * 16;
          av[m] = *(const bf16x8*)(As + row * 128 + ((ks * 64 + akb) ^ axA));
        }
        #pragma unroll
        for (int n = 0; n < NR; ++n) {
          int row = brow_base + n * 16;
          bv[n] = *(const bf16x8*)(Bs + row * 128 + ((ks * 64 + akb) ^ axB));
        }
        #pragma unroll
        for (int m = 0; m < MR; ++m)
          #pragma unroll
          for (int n = 0; n < NR; ++n)
            acc[m][n] = __builtin_amdgcn_mfma_f32_16x16x32_bf16(av[m], bv[n], acc[m][n], 0, 0, 0);
      }
    }
  }

  const int cm = (lane >> 4) * 4;
  const int cn = lane & 15;
  #pragma unroll
  for (int n = 0; n < NR; ++n) {
    int col = nb + wn * WN + n * 16 + cn;
    float bias = 0.f;
    if (d.bias0) bias += d.bias0[col];
    if (d.bias1) bias += d.bias1[col];
    if (d.bias2) bias += d.bias2[col];
    #pragma unroll
    for (int m = 0; m < MR; ++m) {
      #pragma unroll
      for (int j = 0; j < 4; ++j) {
        int row = mb + wm * WM + m * 16 + cm + j;
        float v = acc[m][n][j] + bias;
        if (MODE == 1) {
          ((uint16_t*)d.C)[(size_t)row * d.N + col] = f2b(v);
        } else {
          float o = __shfl_xor(v, 1);
          if (!(lane & 1))
            outp[(size_t)row * (d.N / 2) + (col >> 1)] = fmaxf(v, o) * ymask[row];
        }
      }
    }
  }
}

static inline MDesc mk(const uint16_t* A0, const uint16_t* B0,
                       const uint16_t* A1, const uint16_t* B1,
                       const uint16_t* A2, const uint16_t* B2,
                       const float* b0, const float* b1, const float* b2,
                       float* C, int M, int N, int K)
{
  MDesc d;
  d.A0 = A0; d.B0 = B0; d.A1 = A1; d.B1 = B1; d.A2 = A2; d.B2 = B2;
  d.bias0 = b0; d.bias1 = b1; d.bias2 = b2;
  d.C = C; d.M = M; d.N = N; d.K = K;
  return d;
}

// ------------------------------------------------------------ transposes ----
__global__ __launch_bounds__(256) void transpose_bf16_k(const float* __restrict__ in,
                                                        uint16_t* __restrict__ out,
                                                        int K, int N)
{
  __shared__ float tile[32][33];
  int nx = blockIdx.x * 32, ky = blockIdx.y * 32;
  int tx = threadIdx.x & 31, ty = threadIdx.x >> 5;
  #pragma unroll
  for (int i = 0; i < 4; ++i)
    tile[ty + i * 8][tx] = in[(size_t)(ky + ty + i * 8) * N + nx + tx];
  __syncthreads();
  #pragma unroll
  for (int i = 0; i < 4; ++i)
    out[(size_t)(nx + ty + i * 8) * K + ky + tx] = f2b(tile[tx][ty + i * 8]);
}

__global__ __launch_bounds__(256) void ptranspose_k(const float* __restrict__ in,
                                                    uint16_t* __restrict__ out,
                                                    int K, int N)
{
  __shared__ float tile[32][33];
  int nx = blockIdx.x * 32, ky = blockIdx.y * 32;
  int tx = threadIdx.x & 31, ty = threadIdx.x >> 5;
  #pragma unroll
  for (int i = 0; i < 4; ++i)
    tile[ty + i * 8][tx] = in[(size_t)(ky + ty + i * 8) * N + nx + tx];
  __syncthreads();
  #pragma unroll
  for (int i = 0; i < 4; ++i) {
    int n = nx + ty + i * 8;
    int h = n & 1023, g = n >> 10;
    int np = (h >> 4) * 48 + g * 16 + (h & 15);
    out[(size_t)np * K + ky + tx] = f2b(tile[tx][ty + i * 8]);
  }
}

__global__ __launch_bounds__(256) void pack_k(const float* __restrict__ b1,
                                              const float* __restrict__ b2,
                                              float* __restrict__ b1p,
                                              float* __restrict__ b2p,
                                              int* __restrict__ bar)
{
  int i = blockIdx.x * 256 + threadIdx.x;
  if (i < 1024) bar[i] = 0;
  if (i < H3) {
    int g = (i >> 4) % 3, hblk = i / 48, hi = i & 15;
    int n = g * 1024 + hblk * 16 + hi;
    b1p[i] = b1[n];
    b2p[i] = b2[n];
  }
}

__global__ __launch_bounds__(256) void cvt_bf16_k(const float* __restrict__ in,
                                                  uint16_t* __restrict__ out)
{
  int gid = blockIdx.x * 256 + threadIdx.x;
  float4 v = ((const float4*)in)[gid];
  uint2 o;
  o.x = (uint32_t)f2b(v.x) | ((uint32_t)f2b(v.y) << 16);
  o.y = (uint32_t)f2b(v.z) | ((uint32_t)f2b(v.w) << 16);
  ((uint2*)out)[gid] = o;
}

__global__ __launch_bounds__(256) void embed_k(const int* __restrict__ ys,
                                               const float* __restrict__ emb,
                                               uint16_t* __restrict__ ys_e)
{
  int gid = blockIdx.x * 256 + threadIdx.x;
  int h4 = gid & 255;
  int tb = gid >> 8;
  int tok = ys[tb];
  float4 v = ((const float4*)emb)[(size_t)tok * 256 + h4];
  uint2 o;
  o.x = (uint32_t)f2b(v.x) | ((uint32_t)f2b(v.y) << 16);
  o.y = (uint32_t)f2b(v.z) | ((uint32_t)f2b(v.w) << 16);
  ((uint2*)ys_e)[gid] = o;
}

// ---------------------------------------------------------------- scan ----
struct ScanArgs {
  const uint16_t *U1p, *W2p, *C2p, *U2p;
  const uint16_t *sawt, *ua1t, *ua2t;
  const uint16_t *xw1p;
  const uint16_t *uh_bf, *btg_bf, *xs_bf;
  const uint16_t *stm1_bf;
  const float *s_tm1, *ys_mask, *xs_mask, *a1w, *a1b, *sa_b;
  const float *b2p, *ua1_b, *ua2_b;
  float *sf0, *sf1, *sab_f, *qbuf, *c1f, *c2f, *ahg;
  float *p1part, *p5part, *p2part;
  uint16_t *sab_bf, *c1b, *c2b, *shist_bf, *att_bf;
  int *bar;
};

// Fence-free grid barrier: all data communication goes through agent-scope
// relaxed atomics (cache-bypassing, LLC coherent) so the barrier needs no
// cache maintenance at all — only vmcnt(0) + relaxed counter tree.
__device__ __forceinline__ void gsync(int* bar, int gen, int wg) {
  __syncthreads();
  if (threadIdx.x == 0) {
    asm volatile("s_waitcnt vmcnt(0)" ::: "memory");
    int old = __hip_atomic_fetch_add(bar + (wg & 15) * 32, 1,
                                     __ATOMIC_RELAXED, __HIP_MEMORY_SCOPE_AGENT);
    if (old == gen * 16 - 1) {
      int ro = __hip_atomic_fetch_add(bar + 512, 1,
                                      __ATOMIC_RELAXED, __HIP_MEMORY_SCOPE_AGENT);
      if (ro == gen * 16 - 1)
        __hip_atomic_store(bar + 544, gen, __ATOMIC_RELAXED, __HIP_MEMORY_SCOPE_AGENT);
    }
    while (__hip_atomic_load(bar + 544, __ATOMIC_RELAXED, __HIP_MEMORY_SCOPE_AGENT) < gen)
      __builtin_amdgcn_s_sleep(2);
    asm volatile("s_waitcnt vmcnt(0)" ::: "memory");
  }
  __syncthreads();
}

// LDS map (160 KB dynamic):
//   [0, 131072)       persistent stream cache: this WG's score tensor slice
//                     (uh or btg, fixed b). Row s occupies [s*2048, s*2048+2048):
//                     16B chunk c stored at s*2048 + (c&1)*1024 + (c>>1)*16
//                     (split-half layout -> 16B/lane-stride conflict-free reads).
//                     Rows 0..15 (32 KB) double as P5's buffer B, refilled after P5.
//   [131072, 163840)  32 KB staging: P1/P2q/U2 double-buffered, P5 buffer A
#define STRCACHE 131072
#define HS1 16384   // P1 : 128 rows (dbuf halves at STG+0 / STG+16384)
#define HS2 12288   // P2q: 96 rows
#define HS6 16384   // U2 : 128 rows

// Pair flags: P1 bar[600+pair128], P5 bar[728+pair128], P2 bar[856+pair64].

__global__ __launch_bounds__(256, 1) void scan2_k(ScanArgs a) {
  extern __shared__ char lds[];
  char* stg = lds + STRCACHE;
  const int wg = blockIdx.x;
  const int t = threadIdx.x;
  const int lane = t & 63, w = t >> 6;
  const int r15 = lane & 15;
  const int akb = (lane >> 4) * 16;
  int gen = 0;

  // ---- step-invariant hoists ----
  float wv[16];
  {
    const float* wp = a.a1w + lane * 16;
    #pragma unroll
    for (int j = 0; j < 16; ++j) wv[j] = wp[j];
  }
  const float abv = a.a1b[0];

  // P34 hoists: wg<128 -> e1/c1 via uh; wg>=128 -> e2/c2 via btg. b = wg&127
  const int b34 = wg & 127;
  const uint16_t* src34 = (wg < 128) ? a.uh_bf : a.btg_bf;
  float* cf34 = (wg < 128) ? a.c1f : a.c2f;
  uint16_t* cb34 = (wg < 128) ? a.c1b : a.c2b;
  const uint16_t* xp34 = a.xs_bf + (size_t)b34 * 1024 + t * 4;

  // ---- one-time: fill persistent LDS cache (split-half swizzled layout) ----
  {
    #pragma unroll
    for (int c = 0; c < 32; ++c) {
      int idx = c * 256 + t;
      int s = idx >> 7, hc = idx & 127;
      const uint16_t* gp = src34 + ((size_t)(s * Bdim + b34)) * 1024 + hc * 8;
      *(uint4*)(lds + s * 2048 + (hc & 1) * 1024 + (hc >> 1) * 16) = *(const uint4*)gp;
    }
    __syncthreads();
  }

  // U2-GEMM hoists (active on wg>=128)
  const int bh6 = (wg & 127) >> 6, hb6 = wg & 63;
  const char* ga6[4]; int la6[4];
  {
    #pragma unroll
    for (int c = 0; c < 4; ++c) {
      int i = c * 256 + t;
      int row = i >> 3, kb = (i & 7) * 16;
      if (i < 512) {
        ga6[c] = (const char*)a.sab_bf + ((size_t)(bh6 * 64 + row) * 1024) * 2 + kb;
      } else if (i < 896) {
        int j2 = i - 512; int row2 = j2 >> 3;
        ga6[c] = (const char*)a.U2p + ((size_t)(hb6 * 48 + row2) * 1024) * 2 + kb;
        row = 64 + row2;
      } else {
        ga6[c] = (const char*)a.U2p + kb;   // pad rows 112..127
      }
      la6[c] = row * 128 + (kb ^ ((row & 7) << 4));
    }
  }

  // P1/P5 tile-pair geometry (both halves use wg&127)
  const int bh5 = (wg & 127) >> 6, hblk = wg & 63;
  const int pairid = wg & 127;
  const int koff = (wg < 128) ? 0 : 8;   // K-tile offset for this half

  // P2q pair geometry (active on wg<128): pair64 = wg&63, K-half by wg>=64
  const int p2id = wg & 63;
  const int bh2 = p2id >> 5, nblk = p2id & 31;
  const int koff2 = (wg >= 64 && wg < 128) ? 8 : 0;

  // P5 hoists: 256 rows = c1b(64) c2b(64) W2(48) C2(48) ua1(16) ua2(16)
  const char* ga5[8]; int la5[8];
  {
    #pragma unroll
    for (int c = 0; c < 8; ++c) {
      int i = c * 256 + t;
      int kb = (i & 7) * 16, grow = i >> 3;
      const char* gp;
      if (grow < 64)       gp = (const char*)a.c1b  + ((size_t)(bh5 * 64 + grow)        * 1024) * 2;
      else if (grow < 128) gp = (const char*)a.c2b  + ((size_t)(bh5 * 64 + grow - 64)   * 1024) * 2;
      else if (grow < 176) gp = (const char*)a.W2p  + ((size_t)(hblk * 48 + grow - 128) * 1024) * 2;
      else if (grow < 224) gp = (const char*)a.C2p  + ((size_t)(hblk * 48 + grow - 176) * 1024) * 2;
      else if (grow < 240) gp = (const char*)a.ua1t + ((size_t)(hblk * 16 + grow - 224) * 1024) * 2;
      else                 gp = (const char*)a.ua2t + ((size_t)(hblk * 16 + grow - 240) * 1024) * 2;
      ga5[c] = gp + kb + (size_t)koff * 128;
      la5[c] = grow * 128 + (kb ^ ((grow & 7) << 4));
    }
  }

  unsigned long long* p1p = (unsigned long long*)a.p1part + (size_t)pairid * 1536 + t;
  unsigned long long* p5p = (unsigned long long*)a.p5part + (size_t)pairid * 2048 + t;
  unsigned long long* p2p = (unsigned long long*)a.p2part + (size_t)p2id * 1024 + t;

  for (int step = 0; step < Tdim; ++step) {
    const uint16_t* sprev_bf = step ? (a.shist_bf + (size_t)(step - 1) * Bdim * Hdim) : a.stm1_bf;
    const float* sprev_f = (step == 0) ? a.s_tm1 : ((step & 1) ? a.sf0 : a.sf1);
    float* snext_f = (step & 1) ? a.sf1 : a.sf0;
    const float* ymt = a.ys_mask + (size_t)step * Bdim;
    uint16_t* shist_t = a.shist_bf + (size_t)step * Bdim * Hdim;
    uint16_t* att_t = a.att_bf + (size_t)step * Bdim * Hdim;
    const uint16_t* xw1t = a.xw1p + (size_t)step * Bdim * H3;

    // ===== P1: hg1 = sprev@U1 (gate-packed), K-split across (wg, wg+128) =====
    {
      const char* ga1[4]; int la1[4];
      #pragma unroll
      for (int c = 0; c < 4; ++c) {
        int i = c * 256 + t;
        int row = i >> 3, kb = (i & 7) * 16;
        if (i < 512) {
          ga1[c] = (const char*)sprev_bf + ((size_t)(bh5 * 64 + row) * 1024) * 2 + kb;
        } else if (i < 896) {
          int j2 = i - 512; int row2 = j2 >> 3;
          ga1[c] = (const char*)a.U1p + ((size_t)(hblk * 48 + row2) * 1024) * 2 + kb;
          row = 64 + row2;
        } else {
          ga1[c] = (const char*)a.U1p + kb;  // pad rows 112..127
        }
        ga1[c] += (size_t)koff * 128;
        la1[c] = row * 128 + (kb ^ ((row & 7) << 4));
      }
      f32x4 ac0 = {0.f,0.f,0.f,0.f}, ac1 = ac0, ac2 = ac0;
      const int arow = w * 16 + r15;
      const int axA = (arow & 7) << 4;
      const int axB = (r15 & 7) << 4;
      uint4 rA[4], rB[4];
      auto ld1 = [&](uint4* r, int tile) {
        #pragma unroll
        for (int c = 0; c < 4; ++c)
          r[c] = (c < 2) ? ald128(ga1[c] + (size_t)tile * 128)
                         : *(const uint4*)(ga1[c] + (size_t)tile * 128);
      };
      auto st1 = [&](const uint4* r, int half) {
        char* base = stg + half * HS1;
        #pragma unroll
        for (int c = 0; c < 4; ++c) *(uint4*)(base + la1[c]) = r[c];
      };
      auto cp1 = [&](int half) {
        const char* base = stg + half * HS1;
        #pragma unroll
        for (int ks = 0; ks < 2; ++ks) {
          int ko = ks * 64 + akb;
          bf16x8 av = *(const bf16x8*)(base + arow * 128 + (ko ^ axA));
          bf16x8 b0 = *(const bf16x8*)(base + (64 + r15) * 128 + (ko ^ axB));
          bf16x8 b1 = *(const bf16x8*)(base + (80 + r15) * 128 + (ko ^ axB));
          bf16x8 b2 = *(const bf16x8*)(base + (96 + r15) * 128 + (ko ^ axB));
          ac0 = __builtin_amdgcn_mfma_f32_16x16x32_bf16(av, b0, ac0, 0, 0, 0);
          ac1 = __builtin_amdgcn_mfma_f32_16x16x32_bf16(av, b1, ac1, 0, 0, 0);
          ac2 = __builtin_amdgcn_mfma_f32_16x16x32_bf16(av, b2, ac2, 0, 0, 0);
        }
      };
      ld1(rA, 0); ld1(rB, 1);
      st1(rA, 0);
      #pragma unroll 1
      for (int kk2 = 0; kk2 < 4; ++kk2) {
        __syncthreads();
        st1(rB, 1);
        if (kk2 < 3) ld1(rA, 2 * kk2 + 2);
        cp1(0);
        __syncthreads();
        if (kk2 < 3) { st1(rA, 0); ld1(rB, 2 * kk2 + 3); }
        cp1(1);
      }
      if (wg >= 128) {
        ast64(p1p +    0, PK2(ac0[0], ac0[1]));
        ast64(p1p +  256, PK2(ac0[2], ac0[3]));
        ast64(p1p +  512, PK2(ac1[0], ac1[1]));
        ast64(p1p +  768, PK2(ac1[2], ac1[3]));
        ast64(p1p + 1024, PK2(ac2[0], ac2[1]));
        ast64(p1p + 1280, PK2(ac2[2], ac2[3]));
        __syncthreads();
        if (t == 0)
          __hip_atomic_store(a.bar + 600 + pairid, step + 1,
                             __ATOMIC_RELAXED, __HIP_MEMORY_SCOPE_AGENT);
      } else {
        if (t == 0) {
          while (__hip_atomic_load(a.bar + 600 + pairid,
                                   __ATOMIC_RELAXED, __HIP_MEMORY_SCOPE_AGENT) < step + 1)
            __builtin_amdgcn_s_sleep(1);
        }
        __syncthreads();
        unsigned long long u0 = ald64(p1p), u1 = ald64(p1p + 256),
                           u2 = ald64(p1p + 512), u3 = ald64(p1p + 768),
                           u4 = ald64(p1p + 1024), u5 = ald64(p1p + 1280);
        ac0[0] += ulo(u0); ac0[1] += uhi(u0); ac0[2] += ulo(u1); ac0[3] += uhi(u1);
        ac1[0] += ulo(u2); ac1[1] += uhi(u2); ac1[2] += ulo(u3); ac1[3] += uhi(u3);
        ac2[0] += ulo(u4); ac2[1] += uhi(u4); ac2[2] += ulo(u5); ac2[3] += uhi(u5);
        const int hgl = hblk * 16 + r15;
        const int bbase = bh5 * 64 + w * 16 + ((lane >> 4) << 2);
        #pragma unroll
        for (int j = 0; j < 4; ++j) {
          int b = bbase + j;
          size_t xr_ = (size_t)b * H3 + hblk * 48 + r15;
          float xz = b2f(xw1t[xr_]);
          float xr = b2f(xw1t[xr_ + 16]);
          float xh = b2f(xw1t[xr_ + 32]);
          float hp = aldf(sprev_f + b * 1024 + hgl);
          float z = sigf(xz + ac0[j]);
          float r = sigf(xr + ac1[j]);
          float hn = (1.f - z) * hp + z * tanh_fast(xh + r * ac2[j]);
          float m = ymt[b];
          float o = m * hn + (1.f - m) * hp;
          astf(a.sab_f + b * 1024 + hgl, o);
          uint32_t me = f2b(o);
          uint32_t other = (uint32_t)__shfl_xor((int)me, 1);
          if (!(lane & 1))
            ast32((char*)a.sab_bf + ((size_t)b * 1024 + hgl) * 2, me | (other << 16));
        }
      }
    }
    gsync(a.bar, ++gen, wg);

    // ===== P2-window: q = s_above@sa_w + sa_b, K-split (wg<64 | wg 64..127)
    // =====            hg2 = s_above@U2 -> ahg   (wg>=128) =====
    if (wg < 128) {
      const char* ga2[3]; int la2[3];
      #pragma unroll
      for (int c = 0; c < 3; ++c) {
        int i = c * 256 + t;
        int row, kb = (i & 7) * 16;
        if (i < 512) {
          row = i >> 3;
          ga2[c] = (const char*)a.sab_bf + ((size_t)(bh2 * 64 + row) * 1024) * 2 + kb;
        } else {
          int j2 = i - 512; int row2 = j2 >> 3;
          ga2[c] = (const char*)a.sawt + ((size_t)(nblk * 32 + row2) * 1024) * 2 + kb;
          row = 64 + row2;
        }
        ga2[c] += (size_t)koff2 * 128;
        la2[c] = row * 128 + (kb ^ ((row & 7) << 4));
      }
      f32x4 q0 = {0.f,0.f,0.f,0.f}, q1 = q0;
      const int arow = w * 16 + r15;
      const int axA = (arow & 7) << 4;
      const int axB = (r15 & 7) << 4;
      uint4 rA[3], rB[3];
      auto ld2 = [&](uint4* r, int tile) {
        #pragma unroll
        for (int c = 0; c < 3; ++c)
          r[c] = (c < 2) ? ald128(ga2[c] + (size_t)tile * 128)
                         : *(const uint4*)(ga2[c] + (size_t)tile * 128);
      };
      auto st2 = [&](const uint4* r, int half) {
        char* base = stg + half * HS2;
        #pragma unroll
        for (int c = 0; c < 3; ++c) *(uint4*)(base + la2[c]) = r[c];
      };
      auto cp2 = [&](int half) {
        const char* base = stg + half * HS2;
        #pragma unroll
        for (int ks = 0; ks < 2; ++ks) {
          int ko = ks * 64 + akb;
          bf16x8 av = *(const bf16x8*)(base + arow * 128 + (ko ^ axA));
          bf16x8 b0 = *(const bf16x8*)(base + (64 + r15) * 128 + (ko ^ axB));
          bf16x8 b1 = *(const bf16x8*)(base + (80 + r15) * 128 + (ko ^ axB));
          q0 = __builtin_amdgcn_mfma_f32_16x16x32_bf16(av, b0, q0, 0, 0, 0);
          q1 = __builtin_amdgcn_mfma_f32_16x16x32_bf16(av, b1, q1, 0, 0, 0);
        }
      };
      ld2(rA, 0); ld2(rB, 1);
      st2(rA, 0);
      #pragma unroll 1
      for (int kk2 = 0; kk2 < 4; ++kk2) {
        __syncthreads();
        st2(rB, 1);
        if (kk2 < 3) ld2(rA, 2 * kk2 + 2);
        cp2(0);
        __syncthreads();
        if (kk2 < 3) { st2(rA, 0); ld2(rB, 2 * kk2 + 3); }
        cp2(1);
      }
      if (wg >= 64) {
        ast64(p2p +   0, PK2(q0[0], q0[1]));
        ast64(p2p + 256, PK2(q0[2], q0[3]));
        ast64(p2p + 512, PK2(q1[0], q1[1]));
        ast64(p2p + 768, PK2(q1[2], q1[3]));
        __syncthreads();
        if (t == 0)
          __hip_atomic_store(a.bar + 856 + p2id, step + 1,
                             __ATOMIC_RELAXED, __HIP_MEMORY_SCOPE_AGENT);
      } else {
        if (t == 0) {
          while (__hip_atomic_load(a.bar + 856 + p2id,
                                   __ATOMIC_RELAXED, __HIP_MEMORY_SCOPE_AGENT) < step + 1)
            __builtin_amdgcn_s_sleep(1);
        }
        __syncthreads();
        unsigned long long u0 = ald64(p2p), u1 = ald64(p2p + 256),
                           u2 = ald64(p2p + 512), u3 = ald64(p2p + 768);
        q0[0] += ulo(u0); q0[1] += uhi(u0); q0[2] += ulo(u1); q0[3] += uhi(u1);
        q1[0] += ulo(u2); q1[1] += uhi(u2); q1[2] += ulo(u3); q1[3] += uhi(u3);
        #pragma unroll
        for (int n = 0; n < 2; ++n) {
          int col = nblk * 32 + n * 16 + r15;
          float sb = a.sa_b[col];
          #pragma unroll
          for (int j = 0; j < 4; ++j) {
            int b = bh2 * 64 + w * 16 + ((lane >> 4) << 2) + j;
            astf(a.qbuf + b * 1024 + col, (n ? q1[j] : q0[j]) + sb);
          }
        }
      }
    } else {
      f32x4 ac0 = {0.f,0.f,0.f,0.f}, ac1 = ac0, ac2 = ac0;
      const int arow = w * 16 + r15;
      const int axA = (arow & 7) << 4;
      const int axB = (r15 & 7) << 4;
      uint4 rA[4], rB[4];
      auto ld6 = [&](uint4* r, int tile) {
        #pragma unroll
        for (int c = 0; c < 4; ++c)
          r[c] = (c < 2) ? ald128(ga6[c] + (size_t)tile * 128)
                         : *(const uint4*)(ga6[c] + (size_t)tile * 128);
      };
      auto st6 = [&](const uint4* r, int half) {
        char* base = stg + half * HS6;
        #pragma unroll
        for (int c = 0; c < 4; ++c) *(uint4*)(base + la6[c]) = r[c];
      };
      auto cp6 = [&](int half) {
        const char* base = stg + half * HS6;
        #pragma unroll
        for (int ks = 0; ks < 2; ++ks) {
          int ko = ks * 64 + akb;
          bf16x8 av = *(const bf16x8*)(base + arow * 128 + (ko ^ axA));
          bf16x8 b0 = *(const bf16x8*)(base + (64 + r15) * 128 + (ko ^ axB));
          bf16x8 b1 = *(const bf16x8*)(base + (80 + r15) * 128 + (ko ^ axB));
          bf16x8 b2 = *(const bf16x8*)(base + (96 + r15) * 128 + (ko ^ axB));
          ac0 = __builtin_amdgcn_mfma_f32_16x16x32_bf16(av, b0, ac0, 0, 0, 0);
          ac1 = __builtin_amdgcn_mfma_f32_16x16x32_bf16(av, b1, ac1, 0, 0, 0);
          ac2 = __builtin_amdgcn_mfma_f32_16x16x32_bf16(av, b2, ac2, 0, 0, 0);
        }
      };
      ld6(rA, 0); ld6(rB, 1);
      st6(rA, 0);
      #pragma unroll 1
      for (int kk2 = 0; kk2 < 8; ++kk2) {
        __syncthreads();
        st6(rB, 1);
        if (kk2 < 7) ld6(rA, 2 * kk2 + 2);
        cp6(0);
        __syncthreads();
        if (kk2 < 7) { st6(rA, 0); ld6(rB, 2 * kk2 + 3); }
        cp6(1);
      }
      const int bbase6 = bh6 * 64 + w * 16 + ((lane >> 4) << 2);
      #pragma unroll
      for (int j = 0; j < 4; ++j) {
        int b = bbase6 + j;
        float* ap = a.ahg + (size_t)b * H3 + hb6 * 48 + r15;
        astf(ap, ac0[j]);
        astf(ap + 16, ac1[j]);
        astf(ap + 32, ac2[j]);
      }
    }
    gsync(a.bar, ++gen, wg);

    // ===== P34: scores (tensor slice cached in LDS) + softmax + context =====
    {
      float* e_lds = (float*)stg;
      float qv[16];
      const float* qp = a.qbuf + (size_t)b34 * 1024 + lane * 16;
      #pragma unroll
      for (int k2 = 0; k2 < 8; ++k2) {
        unsigned long long q2 = ald64(qp + k2 * 2);
        qv[2 * k2]     = __uint_as_float((uint32_t)q2);
        qv[2 * k2 + 1] = __uint_as_float((uint32_t)(q2 >> 32));
      }
      #pragma unroll 1
      for (int si = 0; si < 16; ++si) {
        int srow = w * 16 + si;
        const char* rowp = lds + srow * 2048 + lane * 16;
        uint4 u0 = *(const uint4*)rowp;
        uint4 u1 = *(const uint4*)(rowp + 1024);
        float pv = 0.f;
        uint32_t uu[8] = {u0.x,u0.y,u0.z,u0.w,u1.x,u1.y,u1.z,u1.w};
        #pragma unroll
        for (int k = 0; k < 4; ++k) {
          pv += wv[2*k]   * tanh_fast(qv[2*k]   + bl(uu[k]));
          pv += wv[2*k+1] * tanh_fast(qv[2*k+1] + bh(uu[k]));
        }
        #pragma unroll
        for (int k = 4; k < 8; ++k) {
          pv += wv[2*k]   * tanh_fast(qv[2*k]   + bl(uu[k]));
          pv += wv[2*k+1] * tanh_fast(qv[2*k+1] + bh(uu[k]));
        }
        #pragma unroll
        for (int off = 32; off > 0; off >>= 1) pv += __shfl_xor(pv, off);
        if (lane == 0) e_lds[srow] = pv + abv;
      }
      __syncthreads();
      if (w == 0) {
        float vv = e_lds[lane];
        float mx = vv;
        #pragma unroll
        for (int off = 32; off > 0; off >>= 1) mx = fmaxf(mx, __shfl_xor(mx, off));
        float x = __expf(vv - mx) * a.xs_mask[lane * Bdim + b34];
        float sm = x;
        #pragma unroll
        for (int off = 32; off > 0; off >>= 1) sm += __shfl_xor(sm, off);
        e_lds[lane] = x * rcpf(sm + 1e-20f);
      }
      __syncthreads();
      float s0 = 0.f, s1 = 0.f, s2 = 0.f, s3 = 0.f;
      #pragma unroll 8
      for (int s = 0; s < Sdim; ++s) {
        unsigned long long u = *(const unsigned long long*)(xp34 + (size_t)s * Bdim * 1024);
        float aa = e_lds[s];
        s0 += aa * bl((uint32_t)u);
        s1 += aa * bh((uint32_t)u);
        s2 += aa * bl((uint32_t)(u >> 32));
        s3 += aa * bh((uint32_t)(u >> 32));
      }
      size_t o = (size_t)b34 * 1024 + t * 4;
      ast64(cf34 + o,     (unsigned long long)__float_as_uint(s0)
                        | ((unsigned long long)__float_as_uint(s1) << 32));
      ast64(cf34 + o + 2, (unsigned long long)__float_as_uint(s2)
                        | ((unsigned long long)__float_as_uint(s3) << 32));
      unsigned long long pb = (unsigned long long)f2b(s0)
                            | ((unsigned long long)f2b(s1) << 16)
                            | ((unsigned long long)f2b(s2) << 32)
                            | ((unsigned long long)f2b(s3) << 48);
      ast64((char*)cb34 + o * 2, pb);
    }
    // prefetch P5 weight chunks (read-only; overlaps barrier wait) — both halves
    uint4 v5w[8];
    {
      #pragma unroll
      for (int c = 4; c < 8; ++c) {
        v5w[c - 4] = *(const uint4*)ga5[c];
        v5w[c]     = *(const uint4*)(ga5[c] + 128);
      }
    }
    gsync(a.bar, ++gen, wg);

    // ===== P5: xg2/gate MFMA (dbuf: bufA=stg, bufB=cache rows 0..15), K-split =====
    {
      f32x4 ax0 = {0.f,0.f,0.f,0.f}, ax1 = ax0, ax2 = ax0, ag = ax0;
      uint4 rA[8], rB[8];
      auto ld5 = [&](uint4* r, int tile) {
        #pragma unroll
        for (int c = 0; c < 8; ++c)
          r[c] = (c < 4) ? ald128(ga5[c] + (size_t)tile * 128)
                         : *(const uint4*)(ga5[c] + (size_t)tile * 128);
      };
      auto st5 = [&](const uint4* r, int half) {
        char* base = half ? lds : stg;
        #pragma unroll
        for (int c = 0; c < 8; ++c) *(uint4*)(base + la5[c]) = r[c];
      };
      auto cp5 = [&](int half) {
        const char* base = half ? lds : stg;
        #pragma unroll
        for (int ks = 0; ks < 2; ++ks) {
          const int ko = ks * 64 + akb;
          #define LD(row_) (*(const bf16x8*)(base + (row_) * 128 + (ko ^ (((row_) & 7) << 4))))
          bf16x8 a1v = LD(w * 16 + r15);
          bf16x8 a2v = LD(64 + w * 16 + r15);
          bf16x8 bw0 = LD(128 + r15), bw1 = LD(144 + r15), bw2 = LD(160 + r15);
          bf16x8 bc0 = LD(176 + r15), bc1 = LD(192 + r15), bc2 = LD(208 + r15);
          bf16x8 g1v = LD(224 + r15), g2v = LD(240 + r15);
          #undef LD
          ax0 = __builtin_amdgcn_mfma_f32_16x16x32_bf16(a1v, bw0, ax0, 0, 0, 0);
          ax0 = __builtin_amdgcn_mfma_f32_16x16x32_bf16(a2v, bc0, ax0, 0, 0, 0);
          ax1 = __builtin_amdgcn_mfma_f32_16x16x32_bf16(a1v, bw1, ax1, 0, 0, 0);
          ax1 = __builtin_amdgcn_mfma_f32_16x16x32_bf16(a2v, bc1, ax1, 0, 0, 0);
          ax2 = __builtin_amdgcn_mfma_f32_16x16x32_bf16(a1v, bw2, ax2, 0, 0, 0);
          ax2 = __builtin_amdgcn_mfma_f32_16x16x32_bf16(a2v, bc2, ax2, 0, 0, 0);
          ag  = __builtin_amdgcn_mfma_f32_16x16x32_bf16(a1v, g1v, ag, 0, 0, 0);
          ag  = __builtin_amdgcn_mfma_f32_16x16x32_bf16(a2v, g2v, ag, 0, 0, 0);
        }
      };
      #pragma unroll
      for (int c = 0; c < 4; ++c) {
        rA[c] = ald128(ga5[c]);
        rB[c] = ald128(ga5[c] + 128);
      }
      #pragma unroll
      for (int c = 4; c < 8; ++c) { rA[c] = v5w[c - 4]; rB[c] = v5w[c]; }
      st5(rA, 0);
      #pragma unroll 1
      for (int kk2 = 0; kk2 < 4; ++kk2) {
        __syncthreads();
        st5(rB, 1);
        if (kk2 < 3) ld5(rA, 2 * kk2 + 2);
        cp5(0);
        __syncthreads();
        if (kk2 < 3) { st5(rA, 0); ld5(rB, 2 * kk2 + 3); }
        cp5(1);
      }
      if (wg >= 128) {
        ast64(p5p +    0, PK2(ax0[0], ax0[1]));
        ast64(p5p +  256, PK2(ax0[2], ax0[3]));
        ast64(p5p +  512, PK2(ax1[0], ax1[1]));
        ast64(p5p +  768, PK2(ax1[2], ax1[3]));
        ast64(p5p + 1024, PK2(ax2[0], ax2[1]));
        ast64(p5p + 1280, PK2(ax2[2], ax2[3]));
        ast64(p5p + 1536, PK2(ag[0], ag[1]));
        ast64(p5p + 1792, PK2(ag[2], ag[3]));
        __syncthreads();
        if (t == 0)
          __hip_atomic_store(a.bar + 728 + pairid, step + 1,
                             __ATOMIC_RELAXED, __HIP_MEMORY_SCOPE_AGENT);
      } else {
        if (t == 0) {
          while (__hip_atomic_load(a.bar + 728 + pairid,
                                   __ATOMIC_RELAXED, __HIP_MEMORY_SCOPE_AGENT) < step + 1)
            __builtin_amdgcn_s_sleep(1);
        }
        __syncthreads();
        unsigned long long u0 = ald64(p5p), u1 = ald64(p5p + 256),
                           u2 = ald64(p5p + 512), u3 = ald64(p5p + 768),
                           u4 = ald64(p5p + 1024), u5 = ald64(p5p + 1280),
                           u6 = ald64(p5p + 1536), u7 = ald64(p5p + 1792);
        ax0[0] += ulo(u0); ax0[1] += uhi(u0); ax0[2] += ulo(u1); ax0[3] += uhi(u1);
        ax1[0] += ulo(u2); ax1[1] += uhi(u2); ax1[2] += ulo(u3); ax1[3] += uhi(u3);
        ax2[0] += ulo(u4); ax2[1] += uhi(u4); ax2[2] += ulo(u5); ax2[3] += uhi(u5);
        ag[0]  += ulo(u6); ag[1]  += uhi(u6); ag[2]  += ulo(u7); ag[3]  += uhi(u7);
        const int hgl = hblk * 16 + r15;
        float bz  = a.b2p[hblk * 48 + r15];
        float brr = a.b2p[hblk * 48 + 16 + r15];
        float bhh = a.b2p[hblk * 48 + 32 + r15];
        float gb  = a.ua1_b[hgl] + a.ua2_b[hgl];
        const int bbase = bh5 * 64 + w * 16 + ((lane >> 4) << 2);
        float ahz[4], ahr[4], ahh[4], hpv[4], c1v[4], c2v[4];
        #pragma unroll
        for (int j = 0; j < 4; ++j) {
          int b = bbase + j;
          const float* ap = a.ahg + (size_t)b * H3 + hblk * 48 + r15;
          ahz[j] = aldf(ap);
          ahr[j] = aldf(ap + 16);
          ahh[j] = aldf(ap + 32);
          hpv[j] = aldf(a.sab_f + (size_t)b * 1024 + hgl);
          c1v[j] = aldf(a.c1f + (size_t)b * 1024 + hgl);
          c2v[j] = aldf(a.c2f + (size_t)b * 1024 + hgl);
        }
        #pragma unroll
        for (int j = 0; j < 4; ++j) {
          int b = bbase + j;
          float hp = hpv[j];
          float z = sigf(ax0[j] + bz + ahz[j]);
          float r = sigf(ax1[j] + brr + ahr[j]);
          float hn = (1.f - z) * hp + z * tanh_fast(ax2[j] + bhh + r * ahh[j]);
          float m = ymt[b];
          float st = m * hn + (1.f - m) * hp;
          astf(snext_f + b * 1024 + hgl, st);
          uint32_t me = f2b(st);
          uint32_t other = (uint32_t)__shfl_xor((int)me, 1);
          if (!(lane & 1))
            ast32((char*)shist_t + ((size_t)b * 1024 + hgl) * 2, me | (other << 16));
          float g = sigf(ag[j] + gb);
          float att = g * c1v[j] + (1.f - g) * c2v[j];
          att_t[(size_t)b * 1024 + hgl] = f2b(att);
        }
      }
      // refill cache rows 0..15 (overwritten as P5 bufB). Ordered after all
      // cp5 reads by the __syncthreads in both branches above; the following
      // gsync orders these writes before next-step P34 reads.
      #pragma unroll
      for (int c = 0; c < 8; ++c) {
        int idx = c * 256 + t;
        int s = idx >> 7, hc = idx & 127;
        const uint16_t* gp = src34 + ((size_t)(s * Bdim + b34)) * 1024 + hc * 8;
        *(uint4*)(lds + s * 2048 + (hc & 1) * 1024 + (hc >> 1) * 16) = *(const uint4*)gp;
      }
    }
    gsync(a.bar, ++gen, wg);
  }
}

// ---------------------------------------------------------------- host ----
extern "C" void kernel_launch(void* const* d_in, const int* in_sizes, int n_in,
                              void* d_out, int out_size, void* d_ws, size_t ws_size,
                              hipStream_t stream)
{
  const int*   ys      = (const int*)  d_in[0];
  const float* xs_h    = (const float*)d_in[1];
  const float* uh      = (const float*)d_in[2];
  const float* xs_mask = (const float*)d_in[3];
  const float* ys_mask = (const float*)d_in[4];
  const float* s_tm1   = (const float*)d_in[5];
  const float* emb     = (const float*)d_in[6];
  const float* sa_w    = (const float*)d_in[7];
  const float* sa_b    = (const float*)d_in[8];
  const float* a1_w    = (const float*)d_in[9];
  const float* a1_b    = (const float*)d_in[10];
  const float* ha_w    = (const float*)d_in[11];
  const float* ha_b    = (const float*)d_in[12];
  const float* W1      = (const float*)d_in[13];
  const float* U1      = (const float*)d_in[14];
  const float* b1      = (const float*)d_in[15];
  const float* W2      = (const float*)d_in[16];
  const float* U2      = (const float*)d_in[17];
  const float* C2      = (const float*)d_in[18];
  const float* b2      = (const float*)d_in[19];
  const float* ua1_w   = (const float*)d_in[20];
  const float* ua1_b   = (const float*)d_in[21];
  const float* ua2_w   = (const float*)d_in[22];
  const float* ua2_b   = (const float*)d_in[23];
  const float* ls_w    = (const float*)d_in[24];
  const float* ls_b    = (const float*)d_in[25];
  const float* ly_w    = (const float*)d_in[26];
  const float* ly_b    = (const float*)d_in[27];
  const float* lc_w    = (const float*)d_in[28];
  const float* lc_b    = (const float*)d_in[29];
  (void)in_sizes; (void)n_in; (void)out_size; (void)ws_size;

  float* out = (float*)d_out;

  char* wp = (char*)d_ws;
  auto alloc = [&](size_t bytes) { char* r = wp; wp += (bytes + 255) & ~(size_t)255; return r; };

  uint16_t* W1p  = (uint16_t*)alloc((size_t)H3 * Hdim * 2);
  uint16_t* U1p  = (uint16_t*)alloc((size_t)H3 * Hdim * 2);
  uint16_t* W2p  = (uint16_t*)alloc((size_t)H3 * Hdim * 2);
  uint16_t* U2p  = (uint16_t*)alloc((size_t)H3 * Hdim * 2);
  uint16_t* C2p  = (uint16_t*)alloc((size_t)H3 * Hdim * 2);
  uint16_t* sawt = (uint16_t*)alloc((size_t)Hdim * Hdim * 2);
  uint16_t* hawt = (uint16_t*)alloc((size_t)Hdim * Hdim * 2);
  uint16_t* ua1t = (uint16_t*)alloc((size_t)Hdim * Hdim * 2);
  uint16_t* ua2t = (uint16_t*)alloc((size_t)Hdim * Hdim * 2);
  uint16_t* lst  = (uint16_t*)alloc((size_t)2048 * Hdim * 2);
  uint16_t* lyt  = (uint16_t*)alloc((size_t)2048 * Hdim * 2);
  uint16_t* lct  = (uint16_t*)alloc((size_t)2048 * Hdim * 2);
  float* b1p = (float*)alloc((size_t)H3 * 4);
  float* b2p = (float*)alloc((size_t)H3 * 4);
  int* bar   = (int*)alloc(4096);
  uint16_t* uh_bf   = (uint16_t*)alloc((size_t)SB * Hdim * 2);
  uint16_t* xs_bf   = (uint16_t*)alloc((size_t)SB * Hdim * 2);
  uint16_t* btg_bf  = (uint16_t*)alloc((size_t)SB * Hdim * 2);
  uint16_t* ys_e_bf = (uint16_t*)alloc((size_t)TB * Hdim * 2);
  uint16_t* xw1p    = (uint16_t*)alloc((size_t)TB * H3 * 2);
  uint16_t* shist_bf= (uint16_t*)alloc((size_t)TB * Hdim * 2);
  uint16_t* att_bf  = (uint16_t*)alloc((size_t)TB * Hdim * 2);
  uint16_t* stm1_bf = (uint16_t*)alloc((size_t)Bdim * Hdim * 2);
  float* sab_f = (float*)alloc((size_t)Bdim * Hdim * 4);
  uint16_t* sab_bf = (uint16_t*)alloc((size_t)Bdim * Hdim * 2);
  float* qbuf = (float*)alloc((size_t)Bdim * Hdim * 4);
  float* c1f  = (float*)alloc((size_t)Bdim * Hdim * 4);
  float* c2f  = (float*)alloc((size_t)Bdim * Hdim * 4);
  uint16_t* c1b = (uint16_t*)alloc((size_t)Bdim * Hdim * 2);
  uint16_t* c2b = (uint16_t*)alloc((size_t)Bdim * Hdim * 2);
  float* sf0 = (float*)alloc((size_t)Bdim * Hdim * 4);
  float* sf1 = (float*)alloc((size_t)Bdim * Hdim * 4);
  float* ahg = (float*)alloc((size_t)Bdim * H3 * 4);
  float* p1part = (float*)alloc((size_t)128 * 1536 * 8);
  float* p5part = (float*)alloc((size_t)128 * 2048 * 8);
  float* p2part = (float*)alloc((size_t)64 * 1024 * 8);

  // ---- preamble ----
  pack_k<<<12, 256, 0, stream>>>(b1, b2, b1p, b2p, bar);

  auto ptr3 = [&](const float* in, uint16_t* o) {
    ptranspose_k<<<dim3(H3 / 32, Hdim / 32), 256, 0, stream>>>(in, o, Hdim, H3);
  };
  ptr3(W1, W1p); ptr3(U1, U1p); ptr3(W2, W2p); ptr3(U2, U2p); ptr3(C2, C2p);

  auto tr = [&](const float* in, uint16_t* o, int K, int N) {
    transpose_bf16_k<<<dim3(N / 32, K / 32), 256, 0, stream>>>(in, o, K, N);
  };
  tr(sa_w, sawt, Hdim, Hdim); tr(ha_w, hawt, Hdim, Hdim);
  tr(ua1_w, ua1t, Hdim, Hdim); tr(ua2_w, ua2t, Hdim, Hdim);
  tr(ls_w, lst, Hdim, 2048); tr(ly_w, lyt, Hdim, 2048); tr(lc_w, lct, Hdim, 2048);

  cvt_bf16_k<<<(SB * Hdim / 4) / 256, 256, 0, stream>>>(uh, uh_bf);
  cvt_bf16_k<<<(SB * Hdim / 4) / 256, 256, 0, stream>>>(xs_h, xs_bf);
  cvt_bf16_k<<<(Bdim * Hdim / 4) / 256, 256, 0, stream>>>(s_tm1, stm1_bf);
  embed_k<<<(TB * Hdim / 4) / 256, 256, 0, stream>>>(ys, emb, ys_e_bf);

  {  // xw1p = ys_e @ W1p + b1p (bf16, gate-packed cols)
    MDesc d = mk(ys_e_bf, W1p, 0, 0, 0, 0, b1p, 0, 0, (float*)xw1p, TB, H3, Hdim);
    mgemm<128, 128, 1><<<dim3(H3 / 128, TB / 128), 256, 0, stream>>>(d, nullptr, nullptr);
  }
  {  // btg_bf = xs_h @ ha_w + ha_b
    MDesc d = mk(xs_bf, hawt, 0, 0, 0, 0, ha_b, 0, 0, (float*)btg_bf, SB, Hdim, Hdim);
    mgemm<128, 128, 1><<<dim3(Hdim / 128, SB / 128), 256, 0, stream>>>(d, nullptr, nullptr);
  }

  // ---- persistent scan (160 KB dynamic LDS: 128 KB stream cache + 32 KB stage) ----
  static bool attr_set = false;
  if (!attr_set) {
    hipFuncSetAttribute((const void*)scan2_k,
                        hipFuncAttributeMaxDynamicSharedMemorySize, 163840);
    attr_set = true;
  }
  ScanArgs sa;
  sa.U1p = U1p; sa.W2p = W2p; sa.C2p = C2p; sa.U2p = U2p;
  sa.sawt = sawt; sa.ua1t = ua1t; sa.ua2t = ua2t;
  sa.xw1p = xw1p;
  sa.uh_bf = uh_bf; sa.btg_bf = btg_bf; sa.xs_bf = xs_bf;
  sa.stm1_bf = stm1_bf;
  sa.s_tm1 = s_tm1; sa.ys_mask = ys_mask; sa.xs_mask = xs_mask;
  sa.a1w = a1_w; sa.a1b = a1_b; sa.sa_b = sa_b;
  sa.b2p = b2p; sa.ua1_b = ua1_b; sa.ua2_b = ua2_b;
  sa.sf0 = sf0; sa.sf1 = sf1; sa.sab_f = sab_f; sa.qbuf = qbuf;
  sa.c1f = c1f; sa.c2f = c2f; sa.ahg = ahg;
  sa.p1part = p1part; sa.p5part = p5part; sa.p2part = p2part;
  sa.sab_bf = sab_bf; sa.c1b = c1b; sa.c2b = c2b;
  sa.shist_bf = shist_bf; sa.att_bf = att_bf;
  sa.bar = bar;
  scan2_k<<<NWG, 256, 163840, stream>>>(sa);

  // ---- final logits ----
  {
    MDesc d = mk(shist_bf, lst, ys_e_bf, lyt, att_bf, lct, ls_b, ly_b, lc_b,
                 nullptr, TB, 2048, Hdim);
    mgemm<128, 128, 2><<<dim3(2048 / 128, TB / 128), 256, 0, stream>>>(d, ys_mask, out);
  }
}

// Round 11
// 4892.471 us; speedup vs baseline: 1.0432x; 1.0432x over previous
//
#include <hip/hip_runtime.h>
#include <hip/hip_bf16.h>
#include <cstddef>
#include <cstdint>

#define Sdim 64
#define Tdim 64
#define Bdim 128
#define Hdim 1024
#define H3 3072
#define TB (Tdim * Bdim)
#define SB (Sdim * Bdim)
#define NWG 256

typedef __attribute__((ext_vector_type(4))) float f32x4;
typedef __attribute__((ext_vector_type(8))) short bf16x8;

__device__ __forceinline__ float rcpf(float x) { return __builtin_amdgcn_rcpf(x); }
__device__ __forceinline__ float sigf(float x) { return rcpf(1.0f + __expf(-x)); }
__device__ __forceinline__ float tanh_fast(float x) {
  x = fminf(fmaxf(x, -15.0f), 15.0f);
  float t = __expf(2.0f * x);
  return (t - 1.0f) * rcpf(t + 1.0f);
}
__device__ __forceinline__ float bl(uint32_t u) { return __uint_as_float(u << 16); }
__device__ __forceinline__ float bh(uint32_t u) { return __uint_as_float(u & 0xffff0000u); }
__device__ __forceinline__ float b2f(uint16_t v) { return __uint_as_float((uint32_t)v << 16); }
__device__ __forceinline__ uint16_t f2b(float f) {
  __hip_bfloat16 h = __float2bfloat16(f);
  return *reinterpret_cast<uint16_t*>(&h);
}

// ---- relaxed agent-scope (cache-bypassing, coherent) accessors ----
__device__ __forceinline__ uint32_t ald32(const void* p) {
  return __hip_atomic_load((const uint32_t*)p, __ATOMIC_RELAXED, __HIP_MEMORY_SCOPE_AGENT);
}
__device__ __forceinline__ unsigned long long ald64(const void* p) {
  return __hip_atomic_load((const unsigned long long*)p, __ATOMIC_RELAXED, __HIP_MEMORY_SCOPE_AGENT);
}
__device__ __forceinline__ void ast32(void* p, uint32_t v) {
  __hip_atomic_store((uint32_t*)p, v, __ATOMIC_RELAXED, __HIP_MEMORY_SCOPE_AGENT);
}
__device__ __forceinline__ void ast64(void* p, unsigned long long v) {
  __hip_atomic_store((unsigned long long*)p, v, __ATOMIC_RELAXED, __HIP_MEMORY_SCOPE_AGENT);
}
__device__ __forceinline__ float aldf(const void* p) { return __uint_as_float(ald32(p)); }
__device__ __forceinline__ void astf(void* p, float v) { ast32(p, __float_as_uint(v)); }
__device__ __forceinline__ uint4 ald128(const void* p) {
  unsigned long long a = ald64(p);
  unsigned long long b = ald64((const char*)p + 8);
  uint4 r;
  r.x = (uint32_t)a; r.y = (uint32_t)(a >> 32);
  r.z = (uint32_t)b; r.w = (uint32_t)(b >> 32);
  return r;
}
#define PK2(x, y) ((unsigned long long)__float_as_uint(x) | ((unsigned long long)__float_as_uint(y) << 32))
__device__ __forceinline__ float ulo(unsigned long long u) { return __uint_as_float((uint32_t)u); }
__device__ __forceinline__ float uhi(unsigned long long u) { return __uint_as_float((uint32_t)(u >> 32)); }

// ---------------------------------------------------------------- mgemm ----
struct MDesc {
  const uint16_t* A0; const uint16_t* B0;
  const uint16_t* A1; const uint16_t* B1;
  const uint16_t* A2; const uint16_t* B2;
  const float* bias0; const float* bias1; const float* bias2;
  float* C;
  int M, N, K;
};

template<int BM, int BN, int MODE>
__global__ __launch_bounds__(256) void mgemm(MDesc d, const float* __restrict__ ymask,
                                             float* __restrict__ outp)
{
  const int nb = blockIdx.x * BN;
  const int mb = blockIdx.y * BM;
  if (nb >= d.N || mb >= d.M) return;

  __shared__ char lds[(BM + BN) * 128];
  char* As = lds;
  char* Bs = lds + BM * 128;

  const int t = threadIdx.x;
  const int lane = t & 63;
  const int wid = t >> 6;
  const int wm = wid >> 1, wn = wid & 1;
  constexpr int WM = BM / 2, WN = BN / 2;
  constexpr int MR = WM / 16, NR = WN / 16;
  constexpr int CA = BM / 32;
  constexpr int CB = BN / 32;

  const int arow_base = wm * WM + (lane & 15);
  const int brow_base = wn * WN + (lane & 15);
  const int akb = (lane >> 4) * 16;
  const int axA = (arow_base & 7) << 4;
  const int axB = (brow_base & 7) << 4;

  f32x4 acc[MR][NR];
  #pragma unroll
  for (int m = 0; m < MR; ++m)
    #pragma unroll
    for (int n = 0; n < NR; ++n)
      acc[m][n] = (f32x4){0.f, 0.f, 0.f, 0.f};

  const int K = d.K;
  const int nkt = K / 64;

  #pragma unroll 1
  for (int p = 0; p < 3; ++p) {
    const uint16_t* A = (p == 0) ? d.A0 : (p == 1 ? d.A1 : d.A2);
    const uint16_t* B = (p == 0) ? d.B0 : (p == 1 ? d.B1 : d.B2);
    if (A == nullptr) break;

    const char* gA[CA]; int lA[CA];
    const char* gB[CB]; int lB[CB];
    #pragma unroll
    for (int c = 0; c < CA; ++c) {
      int i = c * 256 + t, row = i >> 3, kb = (i & 7) * 16;
      gA[c] = (const char*)A + (size_t)(mb + row) * K * 2 + kb;
      lA[c] = row * 128 + (kb ^ ((row & 7) << 4));
    }
    #pragma unroll
    for (int c = 0; c < CB; ++c) {
      int i = c * 256 + t, row = i >> 3, kb = (i & 7) * 16;
      gB[c] = (const char*)B + (size_t)(nb + row) * K * 2 + kb;
      lB[c] = row * 128 + (kb ^ ((row & 7) << 4));
    }

    uint4 ra[CA], rb[CB];
    #pragma unroll
    for (int c = 0; c < CA; ++c) ra[c] = *(const uint4*)gA[c];
    #pragma unroll
    for (int c = 0; c < CB; ++c) rb[c] = *(const uint4*)gB[c];

    for (int kk = 0; kk < nkt; ++kk) {
      __syncthreads();
      #pragma unroll
      for (int c = 0; c < CA; ++c) *(uint4*)(As + lA[c]) = ra[c];
      #pragma unroll
      for (int c = 0; c < CB; ++c) *(uint4*)(Bs + lB[c]) = rb[c];
      __syncthreads();
      if (kk + 1 < nkt) {
        #pragma unroll
        for (int c = 0; c < CA; ++c) ra[c] = *(const uint4*)(gA[c] + (size_t)(kk + 1) * 128);
        #pragma unroll
        for (int c = 0; c < CB; ++c) rb[c] = *(const uint4*)(gB[c] + (size_t)(kk + 1) * 128);
      }
      #pragma unroll
      for (int ks = 0; ks < 2; ++ks) {
        bf16x8 av[MR], bv[NR];
        #pragma unroll
        for (int m = 0; m < MR; ++m) {
          int row = arow_base + m * 16;
          av[m] = *(const bf16x8*)(As + row * 128 + ((ks * 64 + akb) ^ axA));
        }
        #pragma unroll
        for (int n = 0; n < NR; ++n) {
          int row = brow_base + n * 16;
          bv[n] = *(const bf16x8*)(Bs + row * 128 + ((ks * 64 + akb) ^ axB));
        }
        #pragma unroll
        for (int m = 0; m < MR; ++m)
          #pragma unroll
          for (int n = 0; n < NR; ++n)
            acc[m][n] = __builtin_amdgcn_mfma_f32_16x16x32_bf16(av[m], bv[n], acc[m][n], 0, 0, 0);
      }
    }
  }

  const int cm = (lane >> 4) * 4;
  const int cn = lane & 15;
  #pragma unroll
  for (int n = 0; n < NR; ++n) {
    int col = nb + wn * WN + n * 16 + cn;
    float bias = 0.f;
    if (d.bias0) bias += d.bias0[col];
    if (d.bias1) bias += d.bias1[col];
    if (d.bias2) bias += d.bias2[col];
    #pragma unroll
    for (int m = 0; m < MR; ++m) {
      #pragma unroll
      for (int j = 0; j < 4; ++j) {
        int row = mb + wm * WM + m * 16 + cm + j;
        float v = acc[m][n][j] + bias;
        if (MODE == 1) {
          ((uint16_t*)d.C)[(size_t)row * d.N + col] = f2b(v);
        } else {
          float o = __shfl_xor(v, 1);
          if (!(lane & 1))
            outp[(size_t)row * (d.N / 2) + (col >> 1)] = fmaxf(v, o) * ymask[row];
        }
      }
    }
  }
}

static inline MDesc mk(const uint16_t* A0, const uint16_t* B0,
                       const uint16_t* A1, const uint16_t* B1,
                       const uint16_t* A2, const uint16_t* B2,
                       const float* b0, const float* b1, const float* b2,
                       float* C, int M, int N, int K)
{
  MDesc d;
  d.A0 = A0; d.B0 = B0; d.A1 = A1; d.B1 = B1; d.A2 = A2; d.B2 = B2;
  d.bias0 = b0; d.bias1 = b1; d.bias2 = b2;
  d.C = C; d.M = M; d.N = N; d.K = K;
  return d;
}

// ------------------------------------------------------------ transposes ----
__global__ __launch_bounds__(256) void transpose_bf16_k(const float* __restrict__ in,
                                                        uint16_t* __restrict__ out,
                                                        int K, int N)
{
  __shared__ float tile[32][33];
  int nx = blockIdx.x * 32, ky = blockIdx.y * 32;
  int tx = threadIdx.x & 31, ty = threadIdx.x >> 5;
  #pragma unroll
  for (int i = 0; i < 4; ++i)
    tile[ty + i * 8][tx] = in[(size_t)(ky + ty + i * 8) * N + nx + tx];
  __syncthreads();
  #pragma unroll
  for (int i = 0; i < 4; ++i)
    out[(size_t)(nx + ty + i * 8) * K + ky + tx] = f2b(tile[tx][ty + i * 8]);
}

__global__ __launch_bounds__(256) void ptranspose_k(const float* __restrict__ in,
                                                    uint16_t* __restrict__ out,
                                                    int K, int N)
{
  __shared__ float tile[32][33];
  int nx = blockIdx.x * 32, ky = blockIdx.y * 32;
  int tx = threadIdx.x & 31, ty = threadIdx.x >> 5;
  #pragma unroll
  for (int i = 0; i < 4; ++i)
    tile[ty + i * 8][tx] = in[(size_t)(ky + ty + i * 8) * N + nx + tx];
  __syncthreads();
  #pragma unroll
  for (int i = 0; i < 4; ++i) {
    int n = nx + ty + i * 8;
    int h = n & 1023, g = n >> 10;
    int np = (h >> 4) * 48 + g * 16 + (h & 15);
    out[(size_t)np * K + ky + tx] = f2b(tile[tx][ty + i * 8]);
  }
}

__global__ __launch_bounds__(256) void pack_k(const float* __restrict__ b1,
                                              const float* __restrict__ b2,
                                              float* __restrict__ b1p,
                                              float* __restrict__ b2p,
                                              int* __restrict__ bar)
{
  int i = blockIdx.x * 256 + threadIdx.x;
  if (i < 1024) bar[i] = 0;
  if (i < H3) {
    int g = (i >> 4) % 3, hblk = i / 48, hi = i & 15;
    int n = g * 1024 + hblk * 16 + hi;
    b1p[i] = b1[n];
    b2p[i] = b2[n];
  }
}

__global__ __launch_bounds__(256) void cvt_bf16_k(const float* __restrict__ in,
                                                  uint16_t* __restrict__ out)
{
  int gid = blockIdx.x * 256 + threadIdx.x;
  float4 v = ((const float4*)in)[gid];
  uint2 o;
  o.x = (uint32_t)f2b(v.x) | ((uint32_t)f2b(v.y) << 16);
  o.y = (uint32_t)f2b(v.z) | ((uint32_t)f2b(v.w) << 16);
  ((uint2*)out)[gid] = o;
}

__global__ __launch_bounds__(256) void embed_k(const int* __restrict__ ys,
                                               const float* __restrict__ emb,
                                               uint16_t* __restrict__ ys_e)
{
  int gid = blockIdx.x * 256 + threadIdx.x;
  int h4 = gid & 255;
  int tb = gid >> 8;
  int tok = ys[tb];
  float4 v = ((const float4*)emb)[(size_t)tok * 256 + h4];
  uint2 o;
  o.x = (uint32_t)f2b(v.x) | ((uint32_t)f2b(v.y) << 16);
  o.y = (uint32_t)f2b(v.z) | ((uint32_t)f2b(v.w) << 16);
  ((uint2*)ys_e)[gid] = o;
}

// ---------------------------------------------------------------- scan ----
struct ScanArgs {
  const uint16_t *U1p, *W2p, *C2p, *U2p;
  const uint16_t *sawt, *ua1t, *ua2t;
  const uint16_t *xw1p;
  const uint16_t *uh_bf, *btg_bf, *xs_bf;
  const uint16_t *stm1_bf;
  const float *s_tm1, *ys_mask, *xs_mask, *a1w, *a1b, *sa_b;
  const float *b2p, *ua1_b, *ua2_b;
  float *sf0, *sf1, *sab_f, *qbuf, *c1f, *c2f, *ahg;
  float *p1part, *p5part;
  uint16_t *sab_bf, *c1b, *c2b, *shist_bf, *att_bf;
  int *bar;
};

// Fence-free grid barrier: all data communication goes through agent-scope
// relaxed atomics (cache-bypassing, LLC coherent) so the barrier needs no
// cache maintenance at all — only vmcnt(0) + relaxed counter tree.
__device__ __forceinline__ void gsync(int* bar, int gen, int wg) {
  __syncthreads();
  if (threadIdx.x == 0) {
    asm volatile("s_waitcnt vmcnt(0)" ::: "memory");
    int old = __hip_atomic_fetch_add(bar + (wg & 15) * 32, 1,
                                     __ATOMIC_RELAXED, __HIP_MEMORY_SCOPE_AGENT);
    if (old == gen * 16 - 1) {
      int ro = __hip_atomic_fetch_add(bar + 512, 1,
                                      __ATOMIC_RELAXED, __HIP_MEMORY_SCOPE_AGENT);
      if (ro == gen * 16 - 1)
        __hip_atomic_store(bar + 544, gen, __ATOMIC_RELAXED, __HIP_MEMORY_SCOPE_AGENT);
    }
    while (__hip_atomic_load(bar + 544, __ATOMIC_RELAXED, __HIP_MEMORY_SCOPE_AGENT) < gen)
      __builtin_amdgcn_s_sleep(2);
    asm volatile("s_waitcnt vmcnt(0)" ::: "memory");
  }
  __syncthreads();
}

// LDS map (160 KB dynamic):
//   [0, 131072)       persistent stream cache: this WG's score tensor slice
//                     (uh or btg, fixed b). Row s occupies [s*2048, s*2048+2048):
//                     16B chunk c stored at s*2048 + (c&1)*1024 + (c>>1)*16
//                     (split-half layout -> 16B/lane-stride conflict-free reads).
//   [131072, 163840)  32 KB staging: P1/P2q/U2 double-buffered, P5 single
#define STRCACHE 131072
#define HS1 16384   // P1 : 128 rows (dbuf halves at STG+0 / STG+16384)
#define HS2 12288   // P2q: 96 rows
#define HS6 16384   // U2 : 128 rows
// P5: 256 rows = 32 KB, single buffer at STG

// Pair flags: P1 at bar[600+pair], P5 at bar[728+pair] (bar zeroed by pack_k).

__global__ __launch_bounds__(256, 1) void scan2_k(ScanArgs a) {
  extern __shared__ char lds[];
  char* stg = lds + STRCACHE;
  const int wg = blockIdx.x;
  const int t = threadIdx.x;
  const int lane = t & 63, w = t >> 6;
  const int r15 = lane & 15;
  const int akb = (lane >> 4) * 16;
  int gen = 0;

  // ---- step-invariant hoists ----
  float wv[16];
  {
    const float* wp = a.a1w + lane * 16;
    #pragma unroll
    for (int j = 0; j < 16; ++j) wv[j] = wp[j];
  }
  const float abv = a.a1b[0];

  // P34 hoists: wg<128 -> e1/c1 via uh; wg>=128 -> e2/c2 via btg. b = wg&127
  const int b34 = wg & 127;
  const uint16_t* src34 = (wg < 128) ? a.uh_bf : a.btg_bf;
  float* cf34 = (wg < 128) ? a.c1f : a.c2f;
  uint16_t* cb34 = (wg < 128) ? a.c1b : a.c2b;
  const uint16_t* xp34 = a.xs_bf + (size_t)b34 * 1024 + t * 4;

  // ---- one-time: fill persistent LDS cache (split-half layout) ----
  {
    #pragma unroll
    for (int c = 0; c < 32; ++c) {
      int idx = c * 256 + t;
      int s = idx >> 7, hc = idx & 127;
      const uint16_t* gp = src34 + ((size_t)(s * Bdim + b34)) * 1024 + hc * 8;
      *(uint4*)(lds + s * 2048 + (hc & 1) * 1024 + (hc >> 1) * 16) = *(const uint4*)gp;
    }
    __syncthreads();
  }

  // U2-GEMM hoists (active on wg>=128)
  const int bh6 = (wg & 127) >> 6, hb6 = wg & 63;
  const char* ga6[4]; int la6[4];
  {
    #pragma unroll
    for (int c = 0; c < 4; ++c) {
      int i = c * 256 + t;
      int row = i >> 3, kb = (i & 7) * 16;
      if (i < 512) {
        ga6[c] = (const char*)a.sab_bf + ((size_t)(bh6 * 64 + row) * 1024) * 2 + kb;
      } else if (i < 896) {
        int j2 = i - 512; int row2 = j2 >> 3;
        ga6[c] = (const char*)a.U2p + ((size_t)(hb6 * 48 + row2) * 1024) * 2 + kb;
        row = 64 + row2;
      } else {
        ga6[c] = (const char*)a.U2p + kb;   // pad rows 112..127
      }
      la6[c] = row * 128 + (kb ^ ((row & 7) << 4));
    }
  }

  // P1/P5 tile-pair geometry (both halves use wg&127)
  const int bh5 = (wg & 127) >> 6, hblk = wg & 63;
  const int pairid = wg & 127;
  const int koff = (wg < 128) ? 0 : 8;   // K-tile offset for this half

  // P5 hoists: 256 rows = c1b(64) c2b(64) W2(48) C2(48) ua1(16) ua2(16)
  const char* ga5[8]; int la5[8];
  {
    #pragma unroll
    for (int c = 0; c < 8; ++c) {
      int i = c * 256 + t;
      int kb = (i & 7) * 16, grow = i >> 3;
      const char* gp;
      if (grow < 64)       gp = (const char*)a.c1b  + ((size_t)(bh5 * 64 + grow)        * 1024) * 2;
      else if (grow < 128) gp = (const char*)a.c2b  + ((size_t)(bh5 * 64 + grow - 64)   * 1024) * 2;
      else if (grow < 176) gp = (const char*)a.W2p  + ((size_t)(hblk * 48 + grow - 128) * 1024) * 2;
      else if (grow < 224) gp = (const char*)a.C2p  + ((size_t)(hblk * 48 + grow - 176) * 1024) * 2;
      else if (grow < 240) gp = (const char*)a.ua1t + ((size_t)(hblk * 16 + grow - 224) * 1024) * 2;
      else                 gp = (const char*)a.ua2t + ((size_t)(hblk * 16 + grow - 240) * 1024) * 2;
      ga5[c] = gp + kb + (size_t)koff * 128;
      la5[c] = grow * 128 + (kb ^ ((grow & 7) << 4));
    }
  }

  unsigned long long* p1p = (unsigned long long*)a.p1part + (size_t)pairid * 1536 + t;
  unsigned long long* p5p = (unsigned long long*)a.p5part + (size_t)pairid * 2048 + t;

  for (int step = 0; step < Tdim; ++step) {
    const uint16_t* sprev_bf = step ? (a.shist_bf + (size_t)(step - 1) * Bdim * Hdim) : a.stm1_bf;
    const float* sprev_f = (step == 0) ? a.s_tm1 : ((step & 1) ? a.sf0 : a.sf1);
    float* snext_f = (step & 1) ? a.sf1 : a.sf0;
    const float* ymt = a.ys_mask + (size_t)step * Bdim;
    uint16_t* shist_t = a.shist_bf + (size_t)step * Bdim * Hdim;
    uint16_t* att_t = a.att_bf + (size_t)step * Bdim * Hdim;
    const uint16_t* xw1t = a.xw1p + (size_t)step * Bdim * H3;

    // ===== P1: hg1 = sprev@U1 (gate-packed), K-split across (wg, wg+128) =====
    {
      const char* ga1[4]; int la1[4];
      #pragma unroll
      for (int c = 0; c < 4; ++c) {
        int i = c * 256 + t;
        int row = i >> 3, kb = (i & 7) * 16;
        if (i < 512) {
          ga1[c] = (const char*)sprev_bf + ((size_t)(bh5 * 64 + row) * 1024) * 2 + kb;
        } else if (i < 896) {
          int j2 = i - 512; int row2 = j2 >> 3;
          ga1[c] = (const char*)a.U1p + ((size_t)(hblk * 48 + row2) * 1024) * 2 + kb;
          row = 64 + row2;
        } else {
          ga1[c] = (const char*)a.U1p + kb;  // pad rows 112..127
        }
        ga1[c] += (size_t)koff * 128;
        la1[c] = row * 128 + (kb ^ ((row & 7) << 4));
      }
      f32x4 ac0 = {0.f,0.f,0.f,0.f}, ac1 = ac0, ac2 = ac0;
      const int arow = w * 16 + r15;
      const int axA = (arow & 7) << 4;
      const int axB = (r15 & 7) << 4;
      uint4 rA[4], rB[4];
      auto ld1 = [&](uint4* r, int tile) {
        #pragma unroll
        for (int c = 0; c < 4; ++c)
          r[c] = (c < 2) ? ald128(ga1[c] + (size_t)tile * 128)
                         : *(const uint4*)(ga1[c] + (size_t)tile * 128);
      };
      auto st1 = [&](const uint4* r, int half) {
        char* base = stg + half * HS1;
        #pragma unroll
        for (int c = 0; c < 4; ++c) *(uint4*)(base + la1[c]) = r[c];
      };
      auto cp1 = [&](int half) {
        const char* base = stg + half * HS1;
        #pragma unroll
        for (int ks = 0; ks < 2; ++ks) {
          int ko = ks * 64 + akb;
          bf16x8 av = *(const bf16x8*)(base + arow * 128 + (ko ^ axA));
          bf16x8 b0 = *(const bf16x8*)(base + (64 + r15) * 128 + (ko ^ axB));
          bf16x8 b1 = *(const bf16x8*)(base + (80 + r15) * 128 + (ko ^ axB));
          bf16x8 b2 = *(const bf16x8*)(base + (96 + r15) * 128 + (ko ^ axB));
          ac0 = __builtin_amdgcn_mfma_f32_16x16x32_bf16(av, b0, ac0, 0, 0, 0);
          ac1 = __builtin_amdgcn_mfma_f32_16x16x32_bf16(av, b1, ac1, 0, 0, 0);
          ac2 = __builtin_amdgcn_mfma_f32_16x16x32_bf16(av, b2, ac2, 0, 0, 0);
        }
      };
      ld1(rA, 0); ld1(rB, 1);
      st1(rA, 0);
      #pragma unroll 1
      for (int kk2 = 0; kk2 < 4; ++kk2) {
        __syncthreads();
        st1(rB, 1);
        if (kk2 < 3) ld1(rA, 2 * kk2 + 2);
        cp1(0);
        __syncthreads();
        if (kk2 < 3) { st1(rA, 0); ld1(rB, 2 * kk2 + 3); }
        cp1(1);
      }
      if (wg >= 128) {
        ast64(p1p +    0, PK2(ac0[0], ac0[1]));
        ast64(p1p +  256, PK2(ac0[2], ac0[3]));
        ast64(p1p +  512, PK2(ac1[0], ac1[1]));
        ast64(p1p +  768, PK2(ac1[2], ac1[3]));
        ast64(p1p + 1024, PK2(ac2[0], ac2[1]));
        ast64(p1p + 1280, PK2(ac2[2], ac2[3]));
        __syncthreads();
        if (t == 0)
          __hip_atomic_store(a.bar + 600 + pairid, step + 1,
                             __ATOMIC_RELAXED, __HIP_MEMORY_SCOPE_AGENT);
      } else {
        if (t == 0) {
          while (__hip_atomic_load(a.bar + 600 + pairid,
                                   __ATOMIC_RELAXED, __HIP_MEMORY_SCOPE_AGENT) < step + 1)
            __builtin_amdgcn_s_sleep(1);
        }
        __syncthreads();
        unsigned long long u0 = ald64(p1p), u1 = ald64(p1p + 256),
                           u2 = ald64(p1p + 512), u3 = ald64(p1p + 768),
                           u4 = ald64(p1p + 1024), u5 = ald64(p1p + 1280);
        ac0[0] += ulo(u0); ac0[1] += uhi(u0); ac0[2] += ulo(u1); ac0[3] += uhi(u1);
        ac1[0] += ulo(u2); ac1[1] += uhi(u2); ac1[2] += ulo(u3); ac1[3] += uhi(u3);
        ac2[0] += ulo(u4); ac2[1] += uhi(u4); ac2[2] += ulo(u5); ac2[3] += uhi(u5);
        const int hgl = hblk * 16 + r15;
        const int bbase = bh5 * 64 + w * 16 + ((lane >> 4) << 2);
        #pragma unroll
        for (int j = 0; j < 4; ++j) {
          int b = bbase + j;
          size_t xr_ = (size_t)b * H3 + hblk * 48 + r15;
          float xz = b2f(xw1t[xr_]);
          float xr = b2f(xw1t[xr_ + 16]);
          float xh = b2f(xw1t[xr_ + 32]);
          float hp = aldf(sprev_f + b * 1024 + hgl);
          float z = sigf(xz + ac0[j]);
          float r = sigf(xr + ac1[j]);
          float hn = (1.f - z) * hp + z * tanh_fast(xh + r * ac2[j]);
          float m = ymt[b];
          float o = m * hn + (1.f - m) * hp;
          astf(a.sab_f + b * 1024 + hgl, o);
          uint32_t me = f2b(o);
          uint32_t other = (uint32_t)__shfl_xor((int)me, 1);
          if (!(lane & 1))
            ast32((char*)a.sab_bf + ((size_t)b * 1024 + hgl) * 2, me | (other << 16));
        }
      }
    }
    gsync(a.bar, ++gen, wg);

    // ===== P2-window: q = s_above@sa_w + sa_b (wg<64)
    // =====            hg2 = s_above@U2 -> ahg   (wg>=128) =====
    if (wg < 64) {
      const int bh2 = wg >> 5, nblk = wg & 31;
      const char* ga2[3]; int la2[3];
      #pragma unroll
      for (int c = 0; c < 3; ++c) {
        int i = c * 256 + t;
        int row, kb = (i & 7) * 16;
        if (i < 512) {
          row = i >> 3;
          ga2[c] = (const char*)a.sab_bf + ((size_t)(bh2 * 64 + row) * 1024) * 2 + kb;
        } else {
          int j2 = i - 512; int row2 = j2 >> 3;
          ga2[c] = (const char*)a.sawt + ((size_t)(nblk * 32 + row2) * 1024) * 2 + kb;
          row = 64 + row2;
        }
        la2[c] = row * 128 + (kb ^ ((row & 7) << 4));
      }
      f32x4 q0 = {0.f,0.f,0.f,0.f}, q1 = q0;
      const int arow = w * 16 + r15;
      const int axA = (arow & 7) << 4;
      const int axB = (r15 & 7) << 4;
      uint4 rA[3], rB[3];
      auto ld2 = [&](uint4* r, int tile) {
        #pragma unroll
        for (int c = 0; c < 3; ++c)
          r[c] = (c < 2) ? ald128(ga2[c] + (size_t)tile * 128)
                         : *(const uint4*)(ga2[c] + (size_t)tile * 128);
      };
      auto st2 = [&](const uint4* r, int half) {
        char* base = stg + half * HS2;
        #pragma unroll
        for (int c = 0; c < 3; ++c) *(uint4*)(base + la2[c]) = r[c];
      };
      auto cp2 = [&](int half) {
        const char* base = stg + half * HS2;
        #pragma unroll
        for (int ks = 0; ks < 2; ++ks) {
          int ko = ks * 64 + akb;
          bf16x8 av = *(const bf16x8*)(base + arow * 128 + (ko ^ axA));
          bf16x8 b0 = *(const bf16x8*)(base + (64 + r15) * 128 + (ko ^ axB));
          bf16x8 b1 = *(const bf16x8*)(base + (80 + r15) * 128 + (ko ^ axB));
          q0 = __builtin_amdgcn_mfma_f32_16x16x32_bf16(av, b0, q0, 0, 0, 0);
          q1 = __builtin_amdgcn_mfma_f32_16x16x32_bf16(av, b1, q1, 0, 0, 0);
        }
      };
      ld2(rA, 0); ld2(rB, 1);
      st2(rA, 0);
      #pragma unroll 1
      for (int kk2 = 0; kk2 < 8; ++kk2) {
        __syncthreads();
        st2(rB, 1);
        if (kk2 < 7) ld2(rA, 2 * kk2 + 2);
        cp2(0);
        __syncthreads();
        if (kk2 < 7) { st2(rA, 0); ld2(rB, 2 * kk2 + 3); }
        cp2(1);
      }
      #pragma unroll
      for (int n = 0; n < 2; ++n) {
        int col = nblk * 32 + n * 16 + r15;
        float sb = a.sa_b[col];
        #pragma unroll
        for (int j = 0; j < 4; ++j) {
          int b = bh2 * 64 + w * 16 + ((lane >> 4) << 2) + j;
          astf(a.qbuf + b * 1024 + col, (n ? q1[j] : q0[j]) + sb);
        }
      }
    } else if (wg >= 128) {
      f32x4 ac0 = {0.f,0.f,0.f,0.f}, ac1 = ac0, ac2 = ac0;
      const int arow = w * 16 + r15;
      const int axA = (arow & 7) << 4;
      const int axB = (r15 & 7) << 4;
      uint4 rA[4], rB[4];
      auto ld6 = [&](uint4* r, int tile) {
        #pragma unroll
        for (int c = 0; c < 4; ++c)
          r[c] = (c < 2) ? ald128(ga6[c] + (size_t)tile * 128)
                         : *(const uint4*)(ga6[c] + (size_t)tile * 128);
      };
      auto st6 = [&](const uint4* r, int half) {
        char* base = stg + half * HS6;
        #pragma unroll
        for (int c = 0; c < 4; ++c) *(uint4*)(base + la6[c]) = r[c];
      };
      auto cp6 = [&](int half) {
        const char* base = stg + half * HS6;
        #pragma unroll
        for (int ks = 0; ks < 2; ++ks) {
          int ko = ks * 64 + akb;
          bf16x8 av = *(const bf16x8*)(base + arow * 128 + (ko ^ axA));
          bf16x8 b0 = *(const bf16x8*)(base + (64 + r15) * 128 + (ko ^ axB));
          bf16x8 b1 = *(const bf16x8*)(base + (80 + r15) * 128 + (ko ^ axB));
          bf16x8 b2 = *(const bf16x8*)(base + (96 + r15) * 128 + (ko ^ axB));
          ac0 = __builtin_amdgcn_mfma_f32_16x16x32_bf16(av, b0, ac0, 0, 0, 0);
          ac1 = __builtin_amdgcn_mfma_f32_16x16x32_bf16(av, b1, ac1, 0, 0, 0);
          ac2 = __builtin_amdgcn_mfma_f32_16x16x32_bf16(av, b2, ac2, 0, 0, 0);
        }
      };
      ld6(rA, 0); ld6(rB, 1);
      st6(rA, 0);
      #pragma unroll 1
      for (int kk2 = 0; kk2 < 8; ++kk2) {
        __syncthreads();
        st6(rB, 1);
        if (kk2 < 7) ld6(rA, 2 * kk2 + 2);
        cp6(0);
        __syncthreads();
        if (kk2 < 7) { st6(rA, 0); ld6(rB, 2 * kk2 + 3); }
        cp6(1);
      }
      const int bbase6 = bh6 * 64 + w * 16 + ((lane >> 4) << 2);
      #pragma unroll
      for (int j = 0; j < 4; ++j) {
        int b = bbase6 + j;
        float* ap = a.ahg + (size_t)b * H3 + hb6 * 48 + r15;
        astf(ap, ac0[j]);
        astf(ap + 16, ac1[j]);
        astf(ap + 32, ac2[j]);
      }
    }
    gsync(a.bar, ++gen, wg);

    // ===== P34: scores (tensor slice cached in LDS) + softmax + context =====
    {
      float* e_lds = (float*)stg;
      float qv[16];
      const float* qp = a.qbuf + (size_t)b34 * 1024 + lane * 16;
      #pragma unroll
      for (int k2 = 0; k2 < 8; ++k2) {
        unsigned long long q2 = ald64(qp + k2 * 2);
        qv[2 * k2]     = __uint_as_float((uint32_t)q2);
        qv[2 * k2 + 1] = __uint_as_float((uint32_t)(q2 >> 32));
      }
      #pragma unroll 1
      for (int si = 0; si < 16; ++si) {
        int srow = w * 16 + si;
        const char* rowp = lds + srow * 2048 + lane * 16;
        uint4 u0 = *(const uint4*)rowp;
        uint4 u1 = *(const uint4*)(rowp + 1024);
        float pv = 0.f;
        uint32_t uu[8] = {u0.x,u0.y,u0.z,u0.w,u1.x,u1.y,u1.z,u1.w};
        #pragma unroll
        for (int k = 0; k < 8; ++k) {
          pv += wv[2*k]   * tanh_fast(qv[2*k]   + bl(uu[k]));
          pv += wv[2*k+1] * tanh_fast(qv[2*k+1] + bh(uu[k]));
        }
        #pragma unroll
        for (int off = 32; off > 0; off >>= 1) pv += __shfl_xor(pv, off);
        if (lane == 0) e_lds[srow] = pv + abv;
      }
      __syncthreads();
      if (w == 0) {
        float vv = e_lds[lane];
        float mx = vv;
        #pragma unroll
        for (int off = 32; off > 0; off >>= 1) mx = fmaxf(mx, __shfl_xor(mx, off));
        float x = __expf(vv - mx) * a.xs_mask[lane * Bdim + b34];
        float sm = x;
        #pragma unroll
        for (int off = 32; off > 0; off >>= 1) sm += __shfl_xor(sm, off);
        e_lds[lane] = x * rcpf(sm + 1e-20f);
      }
      __syncthreads();
      float s0 = 0.f, s1 = 0.f, s2 = 0.f, s3 = 0.f;
      #pragma unroll 8
      for (int s = 0; s < Sdim; ++s) {
        unsigned long long u = *(const unsigned long long*)(xp34 + (size_t)s * Bdim * 1024);
        float aa = e_lds[s];
        s0 += aa * bl((uint32_t)u);
        s1 += aa * bh((uint32_t)u);
        s2 += aa * bl((uint32_t)(u >> 32));
        s3 += aa * bh((uint32_t)(u >> 32));
      }
      size_t o = (size_t)b34 * 1024 + t * 4;
      ast64(cf34 + o,     (unsigned long long)__float_as_uint(s0)
                        | ((unsigned long long)__float_as_uint(s1) << 32));
      ast64(cf34 + o + 2, (unsigned long long)__float_as_uint(s2)
                        | ((unsigned long long)__float_as_uint(s3) << 32));
      unsigned long long pb = (unsigned long long)f2b(s0)
                            | ((unsigned long long)f2b(s1) << 16)
                            | ((unsigned long long)f2b(s2) << 32)
                            | ((unsigned long long)f2b(s3) << 48);
      ast64((char*)cb34 + o * 2, pb);
    }
    // prefetch P5 weight chunks (read-only; overlaps barrier wait) — both halves
    uint4 v5w[8];
    {
      #pragma unroll
      for (int c = 4; c < 8; ++c) {
        v5w[c - 4] = *(const uint4*)ga5[c];
        v5w[c]     = *(const uint4*)(ga5[c] + 128);
      }
    }
    gsync(a.bar, ++gen, wg);

    // ===== P5: xg2/gate MFMA (single-buffered LDS), K-split; GRU2 on wg<128 =====
    {
      f32x4 ax0 = {0.f,0.f,0.f,0.f}, ax1 = ax0, ax2 = ax0, ag = ax0;
      uint4 rA[8], rB[8];
      auto ld5 = [&](uint4* r, int tile) {
        #pragma unroll
        for (int c = 0; c < 8; ++c)
          r[c] = (c < 4) ? ald128(ga5[c] + (size_t)tile * 128)
                         : *(const uint4*)(ga5[c] + (size_t)tile * 128);
      };
      auto st5 = [&](const uint4* r) {
        #pragma unroll
        for (int c = 0; c < 8; ++c) *(uint4*)(stg + la5[c]) = r[c];
      };
      auto cp5 = [&]() {
        const char* base = stg;
        #pragma unroll
        for (int ks = 0; ks < 2; ++ks) {
          const int ko = ks * 64 + akb;
          #define LD(row_) (*(const bf16x8*)(base + (row_) * 128 + (ko ^ (((row_) & 7) << 4))))
          bf16x8 a1v = LD(w * 16 + r15);
          bf16x8 a2v = LD(64 + w * 16 + r15);
          bf16x8 bw0 = LD(128 + r15), bw1 = LD(144 + r15), bw2 = LD(160 + r15);
          bf16x8 bc0 = LD(176 + r15), bc1 = LD(192 + r15), bc2 = LD(208 + r15);
          bf16x8 g1v = LD(224 + r15), g2v = LD(240 + r15);
          #undef LD
          ax0 = __builtin_amdgcn_mfma_f32_16x16x32_bf16(a1v, bw0, ax0, 0, 0, 0);
          ax0 = __builtin_amdgcn_mfma_f32_16x16x32_bf16(a2v, bc0, ax0, 0, 0, 0);
          ax1 = __builtin_amdgcn_mfma_f32_16x16x32_bf16(a1v, bw1, ax1, 0, 0, 0);
          ax1 = __builtin_amdgcn_mfma_f32_16x16x32_bf16(a2v, bc1, ax1, 0, 0, 0);
          ax2 = __builtin_amdgcn_mfma_f32_16x16x32_bf16(a1v, bw2, ax2, 0, 0, 0);
          ax2 = __builtin_amdgcn_mfma_f32_16x16x32_bf16(a2v, bc2, ax2, 0, 0, 0);
          ag  = __builtin_amdgcn_mfma_f32_16x16x32_bf16(a1v, g1v, ag, 0, 0, 0);
          ag  = __builtin_amdgcn_mfma_f32_16x16x32_bf16(a2v, g2v, ag, 0, 0, 0);
        }
      };
      #pragma unroll
      for (int c = 0; c < 4; ++c) {
        rA[c] = ald128(ga5[c]);
        rB[c] = ald128(ga5[c] + 128);
      }
      #pragma unroll
      for (int c = 4; c < 8; ++c) { rA[c] = v5w[c - 4]; rB[c] = v5w[c]; }
      #pragma unroll 1
      for (int k2 = 0; k2 < 4; ++k2) {
        __syncthreads();
        st5(rA);
        __syncthreads();
        if (k2 < 3) ld5(rA, 2 * k2 + 2);
        cp5();
        __syncthreads();
        st5(rB);
        __syncthreads();
        if (k2 < 3) ld5(rB, 2 * k2 + 3);
        cp5();
      }
      if (wg >= 128) {
        ast64(p5p +    0, PK2(ax0[0], ax0[1]));
        ast64(p5p +  256, PK2(ax0[2], ax0[3]));
        ast64(p5p +  512, PK2(ax1[0], ax1[1]));
        ast64(p5p +  768, PK2(ax1[2], ax1[3]));
        ast64(p5p + 1024, PK2(ax2[0], ax2[1]));
        ast64(p5p + 1280, PK2(ax2[2], ax2[3]));
        ast64(p5p + 1536, PK2(ag[0], ag[1]));
        ast64(p5p + 1792, PK2(ag[2], ag[3]));
        __syncthreads();
        if (t == 0)
          __hip_atomic_store(a.bar + 728 + pairid, step + 1,
                             __ATOMIC_RELAXED, __HIP_MEMORY_SCOPE_AGENT);
      } else {
        if (t == 0) {
          while (__hip_atomic_load(a.bar + 728 + pairid,
                                   __ATOMIC_RELAXED, __HIP_MEMORY_SCOPE_AGENT) < step + 1)
            __builtin_amdgcn_s_sleep(1);
        }
        __syncthreads();
        unsigned long long u0 = ald64(p5p), u1 = ald64(p5p + 256),
                           u2 = ald64(p5p + 512), u3 = ald64(p5p + 768),
                           u4 = ald64(p5p + 1024), u5 = ald64(p5p + 1280),
                           u6 = ald64(p5p + 1536), u7 = ald64(p5p + 1792);
        ax0[0] += ulo(u0); ax0[1] += uhi(u0); ax0[2] += ulo(u1); ax0[3] += uhi(u1);
        ax1[0] += ulo(u2); ax1[1] += uhi(u2); ax1[2] += ulo(u3); ax1[3] += uhi(u3);
        ax2[0] += ulo(u4); ax2[1] += uhi(u4); ax2[2] += ulo(u5); ax2[3] += uhi(u5);
        ag[0]  += ulo(u6); ag[1]  += uhi(u6); ag[2]  += ulo(u7); ag[3]  += uhi(u7);
        const int hgl = hblk * 16 + r15;
        float bz  = a.b2p[hblk * 48 + r15];
        float brr = a.b2p[hblk * 48 + 16 + r15];
        float bhh = a.b2p[hblk * 48 + 32 + r15];
        float gb  = a.ua1_b[hgl] + a.ua2_b[hgl];
        const int bbase = bh5 * 64 + w * 16 + ((lane >> 4) << 2);
        float ahz[4], ahr[4], ahh[4], hpv[4], c1v[4], c2v[4];
        #pragma unroll
        for (int j = 0; j < 4; ++j) {
          int b = bbase + j;
          const float* ap = a.ahg + (size_t)b * H3 + hblk * 48 + r15;
          ahz[j] = aldf(ap);
          ahr[j] = aldf(ap + 16);
          ahh[j] = aldf(ap + 32);
          hpv[j] = aldf(a.sab_f + (size_t)b * 1024 + hgl);
          c1v[j] = aldf(a.c1f + (size_t)b * 1024 + hgl);
          c2v[j] = aldf(a.c2f + (size_t)b * 1024 + hgl);
        }
        #pragma unroll
        for (int j = 0; j < 4; ++j) {
          int b = bbase + j;
          float hp = hpv[j];
          float z = sigf(ax0[j] + bz + ahz[j]);
          float r = sigf(ax1[j] + brr + ahr[j]);
          float hn = (1.f - z) * hp + z * tanh_fast(ax2[j] + bhh + r * ahh[j]);
          float m = ymt[b];
          float st = m * hn + (1.f - m) * hp;
          astf(snext_f + b * 1024 + hgl, st);
          uint32_t me = f2b(st);
          uint32_t other = (uint32_t)__shfl_xor((int)me, 1);
          if (!(lane & 1))
            ast32((char*)shist_t + ((size_t)b * 1024 + hgl) * 2, me | (other << 16));
          float g = sigf(ag[j] + gb);
          float att = g * c1v[j] + (1.f - g) * c2v[j];
          att_t[(size_t)b * 1024 + hgl] = f2b(att);
        }
      }
    }
    gsync(a.bar, ++gen, wg);
  }
}

// ---------------------------------------------------------------- host ----
extern "C" void kernel_launch(void* const* d_in, const int* in_sizes, int n_in,
                              void* d_out, int out_size, void* d_ws, size_t ws_size,
                              hipStream_t stream)
{
  const int*   ys      = (const int*)  d_in[0];
  const float* xs_h    = (const float*)d_in[1];
  const float* uh      = (const float*)d_in[2];
  const float* xs_mask = (const float*)d_in[3];
  const float* ys_mask = (const float*)d_in[4];
  const float* s_tm1   = (const float*)d_in[5];
  const float* emb     = (const float*)d_in[6];
  const float* sa_w    = (const float*)d_in[7];
  const float* sa_b    = (const float*)d_in[8];
  const float* a1_w    = (const float*)d_in[9];
  const float* a1_b    = (const float*)d_in[10];
  const float* ha_w    = (const float*)d_in[11];
  const float* ha_b    = (const float*)d_in[12];
  const float* W1      = (const float*)d_in[13];
  const float* U1      = (const float*)d_in[14];
  const float* b1      = (const float*)d_in[15];
  const float* W2      = (const float*)d_in[16];
  const float* U2      = (const float*)d_in[17];
  const float* C2      = (const float*)d_in[18];
  const float* b2      = (const float*)d_in[19];
  const float* ua1_w   = (const float*)d_in[20];
  const float* ua1_b   = (const float*)d_in[21];
  const float* ua2_w   = (const float*)d_in[22];
  const float* ua2_b   = (const float*)d_in[23];
  const float* ls_w    = (const float*)d_in[24];
  const float* ls_b    = (const float*)d_in[25];
  const float* ly_w    = (const float*)d_in[26];
  const float* ly_b    = (const float*)d_in[27];
  const float* lc_w    = (const float*)d_in[28];
  const float* lc_b    = (const float*)d_in[29];
  (void)in_sizes; (void)n_in; (void)out_size; (void)ws_size;

  float* out = (float*)d_out;

  char* wp = (char*)d_ws;
  auto alloc = [&](size_t bytes) { char* r = wp; wp += (bytes + 255) & ~(size_t)255; return r; };

  uint16_t* W1p  = (uint16_t*)alloc((size_t)H3 * Hdim * 2);
  uint16_t* U1p  = (uint16_t*)alloc((size_t)H3 * Hdim * 2);
  uint16_t* W2p  = (uint16_t*)alloc((size_t)H3 * Hdim * 2);
  uint16_t* U2p  = (uint16_t*)alloc((size_t)H3 * Hdim * 2);
  uint16_t* C2p  = (uint16_t*)alloc((size_t)H3 * Hdim * 2);
  uint16_t* sawt = (uint16_t*)alloc((size_t)Hdim * Hdim * 2);
  uint16_t* hawt = (uint16_t*)alloc((size_t)Hdim * Hdim * 2);
  uint16_t* ua1t = (uint16_t*)alloc((size_t)Hdim * Hdim * 2);
  uint16_t* ua2t = (uint16_t*)alloc((size_t)Hdim * Hdim * 2);
  uint16_t* lst  = (uint16_t*)alloc((size_t)2048 * Hdim * 2);
  uint16_t* lyt  = (uint16_t*)alloc((size_t)2048 * Hdim * 2);
  uint16_t* lct  = (uint16_t*)alloc((size_t)2048 * Hdim * 2);
  float* b1p = (float*)alloc((size_t)H3 * 4);
  float* b2p = (float*)alloc((size_t)H3 * 4);
  int* bar   = (int*)alloc(4096);
  uint16_t* uh_bf   = (uint16_t*)alloc((size_t)SB * Hdim * 2);
  uint16_t* xs_bf   = (uint16_t*)alloc((size_t)SB * Hdim * 2);
  uint16_t* btg_bf  = (uint16_t*)alloc((size_t)SB * Hdim * 2);
  uint16_t* ys_e_bf = (uint16_t*)alloc((size_t)TB * Hdim * 2);
  uint16_t* xw1p    = (uint16_t*)alloc((size_t)TB * H3 * 2);
  uint16_t* shist_bf= (uint16_t*)alloc((size_t)TB * Hdim * 2);
  uint16_t* att_bf  = (uint16_t*)alloc((size_t)TB * Hdim * 2);
  uint16_t* stm1_bf = (uint16_t*)alloc((size_t)Bdim * Hdim * 2);
  float* sab_f = (float*)alloc((size_t)Bdim * Hdim * 4);
  uint16_t* sab_bf = (uint16_t*)alloc((size_t)Bdim * Hdim * 2);
  float* qbuf = (float*)alloc((size_t)Bdim * Hdim * 4);
  float* c1f  = (float*)alloc((size_t)Bdim * Hdim * 4);
  float* c2f  = (float*)alloc((size_t)Bdim * Hdim * 4);
  uint16_t* c1b = (uint16_t*)alloc((size_t)Bdim * Hdim * 2);
  uint16_t* c2b = (uint16_t*)alloc((size_t)Bdim * Hdim * 2);
  float* sf0 = (float*)alloc((size_t)Bdim * Hdim * 4);
  float* sf1 = (float*)alloc((size_t)Bdim * Hdim * 4);
  float* ahg = (float*)alloc((size_t)Bdim * H3 * 4);
  float* p1part = (float*)alloc((size_t)128 * 1536 * 8);
  float* p5part = (float*)alloc((size_t)128 * 2048 * 8);

  // ---- preamble ----
  pack_k<<<12, 256, 0, stream>>>(b1, b2, b1p, b2p, bar);

  auto ptr3 = [&](const float* in, uint16_t* o) {
    ptranspose_k<<<dim3(H3 / 32, Hdim / 32), 256, 0, stream>>>(in, o, Hdim, H3);
  };
  ptr3(W1, W1p); ptr3(U1, U1p); ptr3(W2, W2p); ptr3(U2, U2p); ptr3(C2, C2p);

  auto tr = [&](const float* in, uint16_t* o, int K, int N) {
    transpose_bf16_k<<<dim3(N / 32, K / 32), 256, 0, stream>>>(in, o, K, N);
  };
  tr(sa_w, sawt, Hdim, Hdim); tr(ha_w, hawt, Hdim, Hdim);
  tr(ua1_w, ua1t, Hdim, Hdim); tr(ua2_w, ua2t, Hdim, Hdim);
  tr(ls_w, lst, Hdim, 2048); tr(ly_w, lyt, Hdim, 2048); tr(lc_w, lct, Hdim, 2048);

  cvt_bf16_k<<<(SB * Hdim / 4) / 256, 256, 0, stream>>>(uh, uh_bf);
  cvt_bf16_k<<<(SB * Hdim / 4) / 256, 256, 0, stream>>>(xs_h, xs_bf);
  cvt_bf16_k<<<(Bdim * Hdim / 4) / 256, 256, 0, stream>>>(s_tm1, stm1_bf);
  embed_k<<<(TB * Hdim / 4) / 256, 256, 0, stream>>>(ys, emb, ys_e_bf);

  {  // xw1p = ys_e @ W1p + b1p (bf16, gate-packed cols)
    MDesc d = mk(ys_e_bf, W1p, 0, 0, 0, 0, b1p, 0, 0, (float*)xw1p, TB, H3, Hdim);
    mgemm<128, 128, 1><<<dim3(H3 / 128, TB / 128), 256, 0, stream>>>(d, nullptr, nullptr);
  }
  {  // btg_bf = xs_h @ ha_w + ha_b
    MDesc d = mk(xs_bf, hawt, 0, 0, 0, 0, ha_b, 0, 0, (float*)btg_bf, SB, Hdim, Hdim);
    mgemm<128, 128, 1><<<dim3(Hdim / 128, SB / 128), 256, 0, stream>>>(d, nullptr, nullptr);
  }

  // ---- persistent scan (160 KB dynamic LDS: 128 KB stream cache + 32 KB stage) ----
  static bool attr_set = false;
  if (!attr_set) {
    hipFuncSetAttribute((const void*)scan2_k,
                        hipFuncAttributeMaxDynamicSharedMemorySize, 163840);
    attr_set = true;
  }
  ScanArgs sa;
  sa.U1p = U1p; sa.W2p = W2p; sa.C2p = C2p; sa.U2p = U2p;
  sa.sawt = sawt; sa.ua1t = ua1t; sa.ua2t = ua2t;
  sa.xw1p = xw1p;
  sa.uh_bf = uh_bf; sa.btg_bf = btg_bf; sa.xs_bf = xs_bf;
  sa.stm1_bf = stm1_bf;
  sa.s_tm1 = s_tm1; sa.ys_mask = ys_mask; sa.xs_mask = xs_mask;
  sa.a1w = a1_w; sa.a1b = a1_b; sa.sa_b = sa_b;
  sa.b2p = b2p; sa.ua1_b = ua1_b; sa.ua2_b = ua2_b;
  sa.sf0 = sf0; sa.sf1 = sf1; sa.sab_f = sab_f; sa.qbuf = qbuf;
  sa.c1f = c1f; sa.c2f = c2f; sa.ahg = ahg;
  sa.p1part = p1part; sa.p5part = p5part;
  sa.sab_bf = sab_bf; sa.c1b = c1b; sa.c2b = c2b;
  sa.shist_bf = shist_bf; sa.att_bf = att_bf;
  sa.bar = bar;
  scan2_k<<<NWG, 256, 163840, stream>>>(sa);

  // ---- final logits ----
  {
    MDesc d = mk(shist_bf, lst, ys_e_bf, lyt, att_bf, lct, ls_b, ly_b, lc_b,
                 nullptr, TB, 2048, Hdim);
    mgemm<128, 128, 2><<<dim3(2048 / 128, TB / 128), 256, 0, stream>>>(d, ys_mask, out);
  }
}